// Round 4
// baseline (3097.343 us; speedup 1.0000x reference)
//
#include <hip/hip_runtime.h>
#include <hip/hip_bf16.h>
#include <cmath>

#define T_  64
#define B_  256
#define D_  2000
#define TN_ 3000
#define E_  256
#define H_  256
#define A_  128
#define V_  128
#define PS_ 64
#define PE_ 64
#define S_  128
#define G1N_ 1500
#define G1L_ 4
#define G2N_ 1500
#define G2L_ 6
#define M_  (T_ * B_)
#define KF_ (H_ + V_ + PE_)

typedef __attribute__((ext_vector_type(8))) short short8_t;
typedef __attribute__((ext_vector_type(4))) float floatx4;
typedef _Float16 __attribute__((ext_vector_type(8))) half8_t;

static __device__ __forceinline__ float sigmoidf_(float x) {
    return 1.0f / (1.0f + __expf(-x));
}

static __device__ __forceinline__ void bsplit_(float v, __hip_bfloat16& hi, __hip_bfloat16& lo) {
    hi = __float2bfloat16(v);
    lo = __float2bfloat16(v - __bfloat162float(hi));
}

// ---------------------------------------------------------------------------
// Split-bf16 MFMA GEMM: C = A @ B, A ~ Ahi+Alo, B ~ Bhi+Blo (bf16 planes).
// NPH=3: hi*hi + hi*lo + lo*hi (fp32-grade). NPH=1: hi*hi only (bf16-grade).
// B given as BT[Npad][K] row-major. M mult 128, K mult 32, Npad = nblk*128.
// 256 thr = 4 waves; wave (wm,wn) owns 64x64 = 4x4 frags of 16x16x32.
// LDS fragment-major, lane-linear 16B slots (conflict-free b128 r/w).
// EPI 1: sigmoid col<128 else tanh. OUTMODE 0: f32 Cf (ACCUM adds); 1: split.
// ---------------------------------------------------------------------------
template<int EPI, bool ACCUM, int OUTMODE, int NPH>
__global__ __launch_bounds__(256)
void k_mgemm3(const __hip_bfloat16* __restrict__ Ahi, const __hip_bfloat16* __restrict__ Alo,
              const __hip_bfloat16* __restrict__ Bhi, const __hip_bfloat16* __restrict__ Blo,
              const float* __restrict__ bias, float* __restrict__ Cf,
              __hip_bfloat16* __restrict__ Chi, __hip_bfloat16* __restrict__ Clo,
              int K, int Nreal, int nblk)
{
    __shared__ __align__(16) short As[4096];
    __shared__ __align__(16) short Bs[4096];

    const int tid  = threadIdx.x;
    const int lane = tid & 63;
    const int w    = tid >> 6;
    const int wm   = w >> 1, wn = w & 1;
    const int lr   = lane & 15;
    const int lkc  = lane >> 4;

    const int bx = blockIdx.x;
    const int m0 = (bx / nblk) * 128;
    const int n0 = (bx % nblk) * 128;

    const int fa = 2 * w;
    const size_t aoff0 = (size_t)(m0 + fa * 16 + lr) * K + lkc * 8;
    const size_t aoff1 = aoff0 + (size_t)16 * K;
    const size_t boff0 = (size_t)(n0 + fa * 16 + lr) * K + lkc * 8;
    const size_t boff1 = boff0 + (size_t)16 * K;

    floatx4 acc[4][4];
#pragma unroll
    for (int i = 0; i < 4; ++i)
#pragma unroll
        for (int j = 0; j < 4; ++j) acc[i][j] = floatx4{0.f, 0.f, 0.f, 0.f};

#pragma unroll 1
    for (int ph = 0; ph < NPH; ++ph) {
        const __hip_bfloat16* Ap = (ph == 2) ? Alo : Ahi;
        const __hip_bfloat16* Bp = (ph == 1) ? Blo : Bhi;

        short8_t ra0 = *(const short8_t*)(const void*)(Ap + aoff0);
        short8_t ra1 = *(const short8_t*)(const void*)(Ap + aoff1);
        short8_t rb0 = *(const short8_t*)(const void*)(Bp + boff0);
        short8_t rb1 = *(const short8_t*)(const void*)(Bp + boff1);

        for (int k0 = 0; k0 < K; k0 += 32) {
            __syncthreads();
            *(short8_t*)(void*)&As[(fa    ) * 512 + lane * 8] = ra0;
            *(short8_t*)(void*)&As[(fa + 1) * 512 + lane * 8] = ra1;
            *(short8_t*)(void*)&Bs[(fa    ) * 512 + lane * 8] = rb0;
            *(short8_t*)(void*)&Bs[(fa + 1) * 512 + lane * 8] = rb1;
            __syncthreads();

            if (k0 + 32 < K) {
                int kn = k0 + 32;
                ra0 = *(const short8_t*)(const void*)(Ap + aoff0 + kn);
                ra1 = *(const short8_t*)(const void*)(Ap + aoff1 + kn);
                rb0 = *(const short8_t*)(const void*)(Bp + boff0 + kn);
                rb1 = *(const short8_t*)(const void*)(Bp + boff1 + kn);
            }

            short8_t af[4], bf[4];
#pragma unroll
            for (int i = 0; i < 4; ++i)
                af[i] = *(const short8_t*)(const void*)&As[(wm * 4 + i) * 512 + lane * 8];
#pragma unroll
            for (int j = 0; j < 4; ++j)
                bf[j] = *(const short8_t*)(const void*)&Bs[(wn * 4 + j) * 512 + lane * 8];
#pragma unroll
            for (int i = 0; i < 4; ++i)
#pragma unroll
                for (int j = 0; j < 4; ++j)
                    acc[i][j] = __builtin_amdgcn_mfma_f32_16x16x32_bf16(af[i], bf[j], acc[i][j], 0, 0, 0);
        }
    }

    // C/D layout (m89-verified): col=lane&15, row=(lane>>4)*4+r
#pragma unroll
    for (int i = 0; i < 4; ++i) {
        const int row = m0 + wm * 64 + i * 16 + (lane >> 4) * 4;
#pragma unroll
        for (int j = 0; j < 4; ++j) {
            const int col = n0 + wn * 64 + j * 16 + (lane & 15);
            if (col < Nreal) {
                float bv = bias ? bias[col] : 0.0f;
#pragma unroll
                for (int r = 0; r < 4; ++r) {
                    float v = acc[i][j][r] + bv;
                    if (EPI == 1) v = (col < 128) ? sigmoidf_(v) : tanhf(v);
                    size_t o = (size_t)(row + r) * Nreal + col;
                    if (OUTMODE == 0) {
                        if (ACCUM) v += Cf[o];
                        Cf[o] = v;
                    } else {
                        __hip_bfloat16 h, l;
                        bsplit_(v, h, l);
                        Chi[o] = h; Clo[o] = l;
                    }
                }
            }
        }
    }
}

// ---------------------------------------------------------------------------
// fp32 tiled GEMM (PP = ini_embd @ W2 only)
// ---------------------------------------------------------------------------
template<int BM, int BN, int BK, int TM, int TN>
__global__ __launch_bounds__(256)
void k_gemm(const float* __restrict__ A, const float* __restrict__ B,
            float* __restrict__ C, int M, int N, int K)
{
    __shared__ float As[BK][BM + 4];
    __shared__ float Bs[BK][BN + 4];
    const int tid = threadIdx.y * blockDim.x + threadIdx.x;
    const int m0 = blockIdx.y * BM;
    const int n0 = blockIdx.x * BN;
    float acc[TM][TN];
#pragma unroll
    for (int i = 0; i < TM; ++i)
#pragma unroll
        for (int j = 0; j < TN; ++j) acc[i][j] = 0.0f;
    for (int k0 = 0; k0 < K; k0 += BK) {
#pragma unroll
        for (int i = tid; i < BM * BK; i += 256) {
            int r = i / BK, c = i % BK;
            int m = m0 + r;
            As[c][r] = (m < M) ? A[(size_t)m * K + k0 + c] : 0.0f;
        }
#pragma unroll
        for (int i = tid; i < BK * BN; i += 256) {
            int r = i / BN, c = i % BN;
            Bs[r][c] = B[(size_t)(k0 + r) * N + n0 + c];
        }
        __syncthreads();
#pragma unroll
        for (int kk = 0; kk < BK; ++kk) {
            float a[TM], b[TN];
#pragma unroll
            for (int i = 0; i < TM; ++i) a[i] = As[kk][threadIdx.y * TM + i];
#pragma unroll
            for (int j = 0; j < TN; ++j) b[j] = Bs[kk][threadIdx.x * TN + j];
#pragma unroll
            for (int i = 0; i < TM; ++i)
#pragma unroll
                for (int j = 0; j < TN; ++j) acc[i][j] += a[i] * b[j];
        }
        __syncthreads();
    }
#pragma unroll
    for (int i = 0; i < TM; ++i) {
        int m = m0 + threadIdx.y * TM + i;
        if (m >= M) continue;
#pragma unroll
        for (int j = 0; j < TN; ++j)
            C[(size_t)m * N + n0 + threadIdx.x * TN + j] = acc[i][j];
    }
}

// ---------------------------------------------------------------------------
// Pack / convert / split kernels
// ---------------------------------------------------------------------------
__global__ void k_pack_w2(const float* __restrict__ Wa_w, float* __restrict__ W2)
{
    int idx = blockIdx.x * blockDim.x + threadIdx.x;
    if (idx >= E_ * 2 * A_) return;
    int e = idx / (2 * A_), j = idx % (2 * A_);
    W2[idx] = (j < A_) ? Wa_w[(size_t)e * A_ + j]
                       : Wa_w[(size_t)(E_ + e) * A_ + (j - A_)];
}

__global__ void k_weaT_split(const float* __restrict__ erase_w, const float* __restrict__ add_w,
                             const float* __restrict__ erase_b, const float* __restrict__ add_b,
                             __hip_bfloat16* __restrict__ Whi, __hip_bfloat16* __restrict__ Wlo,
                             float* __restrict__ bea)
{
    int idx = blockIdx.x * blockDim.x + threadIdx.x;
    if (idx < 256 * 256) {
        int n = idx / 256, k = idx % 256;
        float v = (n < V_) ? erase_w[(size_t)k * V_ + n] : add_w[(size_t)k * V_ + (n - V_)];
        bsplit_(v, Whi[idx], Wlo[idx]);
    }
    if (idx < 2 * V_) bea[idx] = (idx < V_) ? erase_b[idx] : add_b[idx - V_];
}

__global__ void k_wih_split(const float* __restrict__ Wih,
                            __hip_bfloat16* __restrict__ hi, __hip_bfloat16* __restrict__ lo)
{
    int idx = blockIdx.x * blockDim.x + threadIdx.x;
    if (idx < 768 * 256) bsplit_(Wih[idx], hi[idx], lo[idx]);
}

__global__ void k_tranHT_split(const float* __restrict__ tranH_w,
                               __hip_bfloat16* __restrict__ hi, __hip_bfloat16* __restrict__ lo)
{
    int idx = blockIdx.x * blockDim.x + threadIdx.x;
    if (idx >= 256 * 320) return;
    int n = idx / 320, k = idx % 320;
    bsplit_(tranH_w[(size_t)k * 256 + n], hi[idx], lo[idx]);
}

__global__ void k_outWT_split(const float* __restrict__ out_w,
                              __hip_bfloat16* __restrict__ hi, __hip_bfloat16* __restrict__ lo)
{
    int idx = blockIdx.x * blockDim.x + threadIdx.x;
    if (idx >= 2048 * 448) return;
    int n = idx / 448, k = idx % 448;
    float v = (n < D_) ? out_w[(size_t)k * D_ + n] : 0.0f;
    bsplit_(v, hi[idx], lo[idx]);
}

__global__ void k_km_split(const float* __restrict__ ini_embd, const int* __restrict__ KMIds,
                           __hip_bfloat16* __restrict__ hi, __hip_bfloat16* __restrict__ lo)
{
    int idx = blockIdx.x * blockDim.x + threadIdx.x;
    if (idx >= S_ * E_) return;
    int s = idx / E_, k = idx % E_;
    bsplit_(ini_embd[(size_t)KMIds[s] * E_ + k], hi[idx], lo[idx]);
}

__global__ void k_embMT_chunk(const float* __restrict__ embG, const int* __restrict__ mapInfo,
                              int c, __hip_bfloat16* __restrict__ hi, __hip_bfloat16* __restrict__ lo)
{
    int idx = blockIdx.x * blockDim.x + threadIdx.x;
    if (idx >= 256 * 1024) return;
    int e = idx >> 10, dd = idx & 1023;
    int d = c * 1024 + dd;
    float v = (d < D_) ? embG[(size_t)mapInfo[d] * E_ + e] : 0.0f;
    bsplit_(v, hi[idx], lo[idx]);
}

__global__ void k_x_chunk(const float* __restrict__ X, int c,
                          __hip_bfloat16* __restrict__ hi, __hip_bfloat16* __restrict__ lo)
{
    int idx = blockIdx.x * blockDim.x + threadIdx.x;
    if (idx >= M_ * 1024) return;
    int m = idx >> 10, dd = idx & 1023;
    int d = c * 1024 + dd;
    float v = (d < D_) ? X[(size_t)m * D_ + d] : 0.0f;
    bsplit_(v, hi[idx], lo[idx]);
}

__global__ void k_split_flat(const float* __restrict__ src, int n,
                             __hip_bfloat16* __restrict__ hi, __hip_bfloat16* __restrict__ lo)
{
    int idx = blockIdx.x * blockDim.x + threadIdx.x;
    if (idx < n) bsplit_(src[idx], hi[idx], lo[idx]);
}

// Whh[j][e] f32 -> W8[e8][j][8] f16  (lane-coalesced 16B chunks along j)
__global__ void k_wpk8(const float* __restrict__ Whh, _Float16* __restrict__ W8)
{
    int idx = blockIdx.x * blockDim.x + threadIdx.x;
    if (idx >= 768 * 256) return;
    int j = idx / 256, e = idx % 256;
    int e8 = e >> 3, i = e & 7;
    W8[((size_t)e8 * 768 + j) * 8 + i] = (_Float16)Whh[idx];
}

__global__ void k_prof(const float* __restrict__ profiles, const float* __restrict__ emP_w,
                       const float* __restrict__ emP_b, float* __restrict__ prof)
{
    int b = blockIdx.x, j = threadIdx.x;
    float acc = emP_b[j];
    for (int k = 0; k < PS_; ++k) acc += profiles[(size_t)b * PS_ + k] * emP_w[(size_t)k * PE_ + j];
    prof[(size_t)b * PE_ + j] = acc;
}

__global__ void k_fill_tp(const float* __restrict__ prof,
                          __hip_bfloat16* __restrict__ At_hi, __hip_bfloat16* __restrict__ At_lo)
{
    int idx = blockIdx.x * blockDim.x + threadIdx.x;
    if (idx >= M_ * PE_) return;
    int m = idx >> 6, pe = idx & 63;
    float v = prof[(size_t)(m & (B_ - 1)) * PE_ + pe];
    size_t o = (size_t)m * 320 + 256 + pe;
    bsplit_(v, At_hi[o], At_lo[o]);
}

// ---------------------------------------------------------------------------
// GRAM group attention
// ---------------------------------------------------------------------------
__global__ void k_group_embed(const float* __restrict__ PP, const float* __restrict__ Wa_b,
                              const float* __restrict__ Ua_w, const float* __restrict__ ini_embd,
                              const int* __restrict__ leaves1, const int* __restrict__ anc1,
                              const int* __restrict__ leaves2, const int* __restrict__ anc2,
                              float* __restrict__ embedG)
{
    int n = blockIdx.x;
    int lane = threadIdx.x;
    const int* lv; const int* ac; int L;
    if (n < G1N_) { L = G1L_; lv = leaves1 + (size_t)n * G1L_; ac = anc1 + (size_t)n * G1L_; }
    else { int n2 = n - G1N_; L = G2L_; lv = leaves2 + (size_t)n2 * G2L_; ac = anc2 + (size_t)n2 * G2L_; }

    float score[6]; int ai[6];
    for (int l = 0; l < L; ++l) {
        int li = lv[l]; int av = ac[l]; ai[l] = av;
        float s = 0.0f;
        for (int a = lane; a < A_; a += 64) {
            float hv = tanhf(PP[(size_t)li * 256 + a] + PP[(size_t)av * 256 + 128 + a] + Wa_b[a]);
            s += hv * Ua_w[a];
        }
        for (int o = 32; o; o >>= 1) s += __shfl_xor(s, o);
        score[l] = s;
    }
    float mx = -1e30f;
    for (int l = 0; l < L; ++l) mx = fmaxf(mx, score[l]);
    float w[6], sum = 0.0f;
    for (int l = 0; l < L; ++l) { w[l] = __expf(score[l] - mx); sum += w[l]; }
    float inv = 1.0f / sum;
    for (int e = lane; e < E_; e += 64) {
        float acc = 0.0f;
        for (int l = 0; l < L; ++l) acc += w[l] * inv * ini_embd[(size_t)ai[l] * E_ + e];
        embedG[(size_t)n * E_ + e] = acc;
    }
}

// ---------------------------------------------------------------------------
// GRU scan v2: grid=B (1 sample/wg/CU), block=768 (12 waves).
// W8[e8][j][8] f16 coalesced; h fp32 in LDS (broadcast reads).
// gx loaded once per step by all threads at loop top (latency hidden).
// ---------------------------------------------------------------------------
__global__ __launch_bounds__(768)
void k_gru2(const float* __restrict__ gx, const half8_t* __restrict__ W8,
            const float* __restrict__ bhh, const int* __restrict__ X_len,
            float* __restrict__ gruo,
            __hip_bfloat16* __restrict__ At_hi, __hip_bfloat16* __restrict__ At_lo)
{
    const int b = blockIdx.x;
    const int tid = threadIdx.x;
    __shared__ float hS[H_];
    __shared__ float ghS[3 * H_];
    __shared__ float gxnS[H_];

    const int len = X_len[b];
    if (tid < H_) hS[tid] = 0.0f;
    __syncthreads();

    const float bj = bhh[tid];

    for (int t = 0; t < T_; ++t) {
        const size_t gb = ((size_t)t * B_ + b) * (3 * H_);
        float gxv = gx[gb + tid];           // issued early, used after acc loop

        float acc = bj;
#pragma unroll
        for (int e8 = 0; e8 < 32; ++e8) {
            half8_t wv = W8[(size_t)e8 * 768 + tid];
            const float* hp = &hS[e8 * 8];
#pragma unroll
            for (int i = 0; i < 8; ++i)
                acc += (float)wv[i] * hp[i];
        }

        if (tid < 512) ghS[tid] = acc + gxv;     // r,z pre-activations complete
        else { ghS[tid] = acc; gxnS[tid - 512] = gxv; }  // n: keep gh, gx separate
        __syncthreads();

        if (tid < H_) {
            float r  = sigmoidf_(ghS[tid]);
            float z  = sigmoidf_(ghS[256 + tid]);
            float nn = tanhf(gxnS[tid] + r * ghS[512 + tid]);
            float hold = hS[tid];
            float hnew = (1.0f - z) * nn + z * hold;
            bool msk = (t < len);
            float hv = msk ? hnew : hold;
            hS[tid] = hv;
            float ov = msk ? hv : 0.0f;
            size_t m = (size_t)t * B_ + b;
            gruo[m * H_ + tid] = ov;
            size_t o = m * 320 + tid;
            bsplit_(ov, At_hi[o], At_lo[o]);
        }
        __syncthreads();
    }
}

// ---------------------------------------------------------------------------
// Value-memory scan
// ---------------------------------------------------------------------------
__global__ __launch_bounds__(256)
void k_mem(const float* __restrict__ slotw, const float* __restrict__ era,
           const float* __restrict__ iniVam, float* __restrict__ readv)
{
    const int b = blockIdx.x;
    const int tid = threadIdx.x;
    const int v = tid & (V_ - 1);
    const int sh = tid >> 7;
    const int sbase = sh * 64;

    float VM[64];
#pragma unroll 8
    for (int i = 0; i < 64; ++i) VM[i] = iniVam[(size_t)(sbase + i) * V_ + v];

    __shared__ float swL[S_];
    __shared__ float eaL[2 * V_];
    __shared__ float part[V_];

    for (int t = 0; t < T_; ++t) {
        size_t m = (size_t)t * B_ + b;
        if (tid < S_) swL[tid] = slotw[m * S_ + tid];
        eaL[tid] = era[m * (2 * V_) + tid];
        __syncthreads();

        float er = eaL[v], ad = eaL[V_ + v];
        float acc = 0.0f;
#pragma unroll 8
        for (int i = 0; i < 64; ++i) {
            float sv = swL[sbase + i];
            float vm = VM[i];
            acc += sv * vm;
            VM[i] = vm * (1.0f - sv * er) + sv * ad;
        }
        if (sh == 1) part[v] = acc;
        __syncthreads();
        if (sh == 0) readv[m * V_ + v] = acc + part[v];
        __syncthreads();
    }
}

// ---------------------------------------------------------------------------
// F = [gruo | read | prof2] as bf16 split planes
// ---------------------------------------------------------------------------
__global__ __launch_bounds__(256)
void k_build_final(const float* __restrict__ gruo, const float* __restrict__ readv,
                   const float* __restrict__ prof, const float* __restrict__ attnP_w,
                   const float* __restrict__ attnP_b,
                   __hip_bfloat16* __restrict__ F_hi, __hip_bfloat16* __restrict__ F_lo)
{
    const int m = blockIdx.x;
    const int b = m & (B_ - 1);
    const int tid = threadIdx.x;
    __shared__ float rd[V_];
    __shared__ float pf[PE_];
    if (tid < V_) rd[tid] = readv[(size_t)m * V_ + tid];
    if (tid < PE_) pf[tid] = prof[(size_t)b * PE_ + tid];
    __syncthreads();

    size_t base = (size_t)m * KF_;
    bsplit_(gruo[(size_t)m * H_ + tid], F_hi[base + tid], F_lo[base + tid]);
    if (tid < V_) bsplit_(rd[tid], F_hi[base + H_ + tid], F_lo[base + H_ + tid]);
    if (tid < PE_) {
        float a = attnP_b[tid];
        for (int k = 0; k < PE_; ++k) a += pf[k] * attnP_w[(size_t)k * PE_ + tid];
        for (int k = 0; k < V_; ++k) a += rd[k] * attnP_w[(size_t)(PE_ + k) * PE_ + tid];
        a = fmaxf(a, 0.0f);
        bsplit_(pf[tid] * a, F_hi[base + H_ + V_ + tid], F_lo[base + H_ + V_ + tid]);
    }
}

// ---------------------------------------------------------------------------
// Softmaxes
// ---------------------------------------------------------------------------
__global__ void k_softmax128(float* __restrict__ C)
{
    const int m = blockIdx.x;
    const size_t base = (size_t)m * S_;
    const int lane = threadIdx.x;
    float a = C[base + lane], b = C[base + 64 + lane];
    float mx = fmaxf(a, b);
    for (int o = 32; o; o >>= 1) mx = fmaxf(mx, __shfl_xor(mx, o));
    float e0 = __expf(a - mx), e1 = __expf(b - mx);
    float s = e0 + e1;
    for (int o = 32; o; o >>= 1) s += __shfl_xor(s, o);
    float inv = 1.0f / s;
    C[base + lane] = e0 * inv;
    C[base + 64 + lane] = e1 * inv;
}

__global__ __launch_bounds__(256)
void k_softmax2000(float* __restrict__ C)
{
    const int m = blockIdx.x;
    const size_t base = (size_t)m * D_;
    const int tid = threadIdx.x;
    const int wid = tid >> 6, lane = tid & 63;
    __shared__ float red[4], red2[4];

    float v[8];
#pragma unroll
    for (int i = 0; i < 8; ++i) {
        int d = i * 256 + tid;
        v[i] = (d < D_) ? C[base + d] : -1e30f;
    }
    float mx = v[0];
#pragma unroll
    for (int i = 1; i < 8; ++i) mx = fmaxf(mx, v[i]);
    for (int o = 32; o; o >>= 1) mx = fmaxf(mx, __shfl_xor(mx, o));
    if (lane == 0) red[wid] = mx;
    __syncthreads();
    mx = fmaxf(fmaxf(red[0], red[1]), fmaxf(red[2], red[3]));

    float sum = 0.0f;
#pragma unroll
    for (int i = 0; i < 8; ++i) { v[i] = __expf(v[i] - mx); sum += v[i]; }
    for (int o = 32; o; o >>= 1) sum += __shfl_xor(sum, o);
    if (lane == 0) red2[wid] = sum;
    __syncthreads();
    sum = red2[0] + red2[1] + red2[2] + red2[3];
    float inv = 1.0f / sum;
#pragma unroll
    for (int i = 0; i < 8; ++i) {
        int d = i * 256 + tid;
        if (d < D_) C[base + d] = v[i] * inv;
    }
}

// ---------------------------------------------------------------------------
// Launch
// ---------------------------------------------------------------------------
extern "C" void kernel_launch(void* const* d_in, const int* in_sizes, int n_in,
                              void* d_out, int out_size, void* d_ws, size_t ws_size,
                              hipStream_t stream)
{
    const float* X        = (const float*)d_in[0];
    const float* profiles = (const float*)d_in[1];
    const float* ini_embd = (const float*)d_in[2];
    const float* Wa_w     = (const float*)d_in[3];
    const float* Wa_b     = (const float*)d_in[4];
    const float* Ua_w     = (const float*)d_in[5];
    const float* gru_Wih  = (const float*)d_in[6];
    const float* gru_Whh  = (const float*)d_in[7];
    const float* gru_bih  = (const float*)d_in[8];
    const float* gru_bhh  = (const float*)d_in[9];
    const float* tranH_w  = (const float*)d_in[10];
    const float* tranH_b  = (const float*)d_in[11];
    const float* out_w    = (const float*)d_in[12];
    const float* out_b    = (const float*)d_in[13];
    const float* erase_w  = (const float*)d_in[14];
    const float* erase_b  = (const float*)d_in[15];
    const float* add_w    = (const float*)d_in[16];
    const float* add_b    = (const float*)d_in[17];
    const float* iniVam   = (const float*)d_in[18];
    const float* emP_w    = (const float*)d_in[19];
    const float* emP_b    = (const float*)d_in[20];
    const float* attnP_w  = (const float*)d_in[21];
    const float* attnP_b  = (const float*)d_in[22];
    const int* KMIds   = (const int*)d_in[23];
    const int* leaves1 = (const int*)d_in[24];
    const int* anc1    = (const int*)d_in[25];
    const int* leaves2 = (const int*)d_in[26];
    const int* anc2    = (const int*)d_in[27];
    const int* mapInfo = (const int*)d_in[28];
    const int* X_len   = (const int*)d_in[29];

    char* ws = (char*)d_ws;
    float* out = (float*)d_out;
    typedef __hip_bfloat16 bf16;

    // ---- workspace layout (bytes) ----
    const size_t R0 = 0;            // 67,108,864 multi-use region
    const size_t R1 = 67108864;     // 16,777,216 : Xe f32; later gruo f32
    const size_t R2 = 83886080;     // 16,777,216 : era f32
    const size_t R3 = 100663296;    // 20,971,520 : At_hi/At_lo; later slotw/readv
    size_t P = 121634816;
    const size_t E0HI = P; P += 524288;
    const size_t E0LO = P; P += 524288;
    const size_t E1HI = P; P += 524288;
    const size_t E1LO = P; P += 524288;
    const size_t OWHI = P; P += 1835008;
    const size_t OWLO = P; P += 1835008;
    const size_t WIHI = P; P += 393216;
    const size_t WILO = P; P += 393216;
    const size_t WEHI = P; P += 131072;
    const size_t WELO = P; P += 131072;
    const size_t THHI = P; P += 163840;
    const size_t THLO = P; P += 163840;
    const size_t KMHI = P; P += 65536;
    const size_t KMLO = P; P += 65536;
    const size_t W8O  = P; P += 393216;   // Whh f16 [32][768][8]
    const size_t PROF = P; P += 65536;
    const size_t BEA  = P; P += 1024;
    const size_t W2O  = P; P += 262144;

    float* PP      = (float*)(ws + R0);
    float* embG    = (float*)(ws + R0 + 12288000);
    bf16*  Xc_hi   = (bf16*)(ws + R0);
    bf16*  Xc_lo   = (bf16*)(ws + R0 + 33554432);
    float* gx      = (float*)(ws + R0);
    bf16*  Xe_hi   = (bf16*)(ws + R0 + 50331648);
    bf16*  Xe_lo   = (bf16*)(ws + R0 + 58720256);
    bf16*  tran_hi = (bf16*)(ws + R0);
    bf16*  tran_lo = (bf16*)(ws + R0 + 8388608);
    bf16*  F_hi    = (bf16*)(ws + R0);
    bf16*  F_lo    = (bf16*)(ws + R0 + 14680064);
    float* Xe_f    = (float*)(ws + R1);
    float* gruo    = (float*)(ws + R1);
    float* era     = (float*)(ws + R2);
    bf16*  At_hi   = (bf16*)(ws + R3);
    bf16*  At_lo   = (bf16*)(ws + R3 + 10485760);
    float* slotw   = (float*)(ws + R3);
    float* readv   = (float*)(ws + R3 + 10485760);
    bf16*  E0hi = (bf16*)(ws + E0HI); bf16* E0lo = (bf16*)(ws + E0LO);
    bf16*  E1hi = (bf16*)(ws + E1HI); bf16* E1lo = (bf16*)(ws + E1LO);
    bf16*  OWhi = (bf16*)(ws + OWHI); bf16* OWlo = (bf16*)(ws + OWLO);
    bf16*  WIhi = (bf16*)(ws + WIHI); bf16* WIlo = (bf16*)(ws + WILO);
    bf16*  WEhi = (bf16*)(ws + WEHI); bf16* WElo = (bf16*)(ws + WELO);
    bf16*  THhi = (bf16*)(ws + THHI); bf16* THlo = (bf16*)(ws + THLO);
    bf16*  KMhi = (bf16*)(ws + KMHI); bf16* KMlo = (bf16*)(ws + KMLO);
    _Float16* W8 = (_Float16*)(ws + W8O);
    float* prof = (float*)(ws + PROF);
    float* bea  = (float*)(ws + BEA);
    float* W2p  = (float*)(ws + W2O);

    // ---- weight packs ----
    k_pack_w2<<<(E_ * 2 * A_ + 255) / 256, 256, 0, stream>>>(Wa_w, W2p);
    k_weaT_split<<<(256 * 256 + 255) / 256, 256, 0, stream>>>(erase_w, add_w, erase_b, add_b, WEhi, WElo, bea);
    k_wih_split<<<(768 * 256 + 255) / 256, 256, 0, stream>>>(gru_Wih, WIhi, WIlo);
    k_tranHT_split<<<(256 * 320 + 255) / 256, 256, 0, stream>>>(tranH_w, THhi, THlo);
    k_outWT_split<<<(2048 * 448 + 255) / 256, 256, 0, stream>>>(out_w, OWhi, OWlo);
    k_km_split<<<(S_ * E_ + 255) / 256, 256, 0, stream>>>(ini_embd, KMIds, KMhi, KMlo);
    k_wpk8<<<(768 * 256 + 255) / 256, 256, 0, stream>>>(gru_Whh, W8);
    k_prof<<<B_, PE_, 0, stream>>>(profiles, emP_w, emP_b, prof);

    // ---- ontology attention -> embedMat ----
    {
        dim3 blk(16, 16);
        dim3 grid(4, (TN_ + 63) / 64);
        k_gemm<64, 64, 16, 4, 4><<<grid, blk, 0, stream>>>(ini_embd, W2p, PP, TN_, 256, E_);
    }
    k_group_embed<<<G1N_ + G2N_, 64, 0, stream>>>(PP, Wa_b, Ua_w, ini_embd,
                                                  leaves1, anc1, leaves2, anc2, embG);
    k_embMT_chunk<<<(256 * 1024) / 256, 256, 0, stream>>>(embG, mapInfo, 0, E0hi, E0lo);
    k_embMT_chunk<<<(256 * 1024) / 256, 256, 0, stream>>>(embG, mapInfo, 1, E1hi, E1lo);

    // ---- Xe = X @ embM (split, K-chunked, fp32 accumulate) ----
    k_x_chunk<<<(M_ * 1024) / 256, 256, 0, stream>>>(X, 0, Xc_hi, Xc_lo);
    k_mgemm3<0, false, 0, 3><<<128 * 2, 256, 0, stream>>>(Xc_hi, Xc_lo, E0hi, E0lo,
        nullptr, Xe_f, nullptr, nullptr, 1024, 256, 2);
    k_x_chunk<<<(M_ * 1024) / 256, 256, 0, stream>>>(X, 1, Xc_hi, Xc_lo);
    k_mgemm3<0, true, 0, 3><<<128 * 2, 256, 0, stream>>>(Xc_hi, Xc_lo, E1hi, E1lo,
        nullptr, Xe_f, nullptr, nullptr, 1024, 256, 2);

    k_split_flat<<<(M_ * 256) / 256, 256, 0, stream>>>(Xe_f, M_ * 256, Xe_hi, Xe_lo);

    // ---- era = gates(Xe @ Wea + bea) ----
    k_mgemm3<1, false, 0, 3><<<128 * 2, 256, 0, stream>>>(Xe_hi, Xe_lo, WEhi, WElo,
        bea, era, nullptr, nullptr, 256, 256, 2);

    // ---- gx = Xe @ Wih^T + bih ----
    k_mgemm3<0, false, 0, 3><<<128 * 6, 256, 0, stream>>>(Xe_hi, Xe_lo, WIhi, WIlo,
        gru_bih, gx, nullptr, nullptr, 256, 768, 6);

    // ---- GRU scan v2 ----
    k_gru2<<<B_, 768, 0, stream>>>(gx, (const half8_t*)W8, gru_bhh, X_len, gruo, At_hi, At_lo);
    k_fill_tp<<<(M_ * PE_) / 256, 256, 0, stream>>>(prof, At_hi, At_lo);

    // ---- tran = [gruo|prof] @ tranH + b ----
    k_mgemm3<0, false, 1, 3><<<128 * 2, 256, 0, stream>>>(At_hi, At_lo, THhi, THlo,
        tranH_b, nullptr, tran_hi, tran_lo, 320, 256, 2);

    // ---- slot logits = tran @ KM^T ----
    k_mgemm3<0, false, 0, 3><<<128 * 1, 256, 0, stream>>>(tran_hi, tran_lo, KMhi, KMlo,
        nullptr, slotw, nullptr, nullptr, 256, 128, 1);

    k_softmax128<<<M_, 64, 0, stream>>>(slotw);
    k_mem<<<B_, 256, 0, stream>>>(slotw, era, iniVam, readv);
    k_build_final<<<M_, 256, 0, stream>>>(gruo, readv, prof, attnP_w, attnP_b, F_hi, F_lo);

    // ---- logits = F @ out_w + out_b (1-phase bf16) ----
    k_mgemm3<0, false, 0, 1><<<128 * 16, 256, 0, stream>>>(F_hi, F_lo, OWhi, OWlo,
        out_b, out, nullptr, nullptr, 448, 2000, 16);

    k_softmax2000<<<M_, 256, 0, stream>>>(out);
}

// Round 5
// 1622.906 us; speedup vs baseline: 1.9085x; 1.9085x over previous
//
#include <hip/hip_runtime.h>
#include <hip/hip_bf16.h>
#include <cmath>

#define T_  64
#define B_  256
#define D_  2000
#define TN_ 3000
#define E_  256
#define H_  256
#define A_  128
#define V_  128
#define PS_ 64
#define PE_ 64
#define S_  128
#define G1N_ 1500
#define G1L_ 4
#define G2N_ 1500
#define G2L_ 6
#define M_  (T_ * B_)
#define KF_ (H_ + V_ + PE_)

typedef __attribute__((ext_vector_type(8))) short short8_t;
typedef __attribute__((ext_vector_type(4))) float floatx4;

static __device__ __forceinline__ float sigmoidf_(float x) {
    return 1.0f / (1.0f + __expf(-x));
}

static __device__ __forceinline__ void bsplit_(float v, __hip_bfloat16& hi, __hip_bfloat16& lo) {
    hi = __float2bfloat16(v);
    lo = __float2bfloat16(v - __bfloat162float(hi));
}

// ---------------------------------------------------------------------------
// Split-bf16 MFMA GEMM: C = A @ B, A ~ Ahi+Alo, B ~ Bhi+Blo (bf16 planes).
// NPH=3: hi*hi + hi*lo + lo*hi (fp32-grade). NPH=1: hi*hi only (bf16-grade).
// B given as BT[Npad][K] row-major. M mult 128, K mult 32, Npad = nblk*128.
// ---------------------------------------------------------------------------
template<int EPI, bool ACCUM, int OUTMODE, int NPH>
__global__ __launch_bounds__(256)
void k_mgemm3(const __hip_bfloat16* __restrict__ Ahi, const __hip_bfloat16* __restrict__ Alo,
              const __hip_bfloat16* __restrict__ Bhi, const __hip_bfloat16* __restrict__ Blo,
              const float* __restrict__ bias, float* __restrict__ Cf,
              __hip_bfloat16* __restrict__ Chi, __hip_bfloat16* __restrict__ Clo,
              int K, int Nreal, int nblk)
{
    __shared__ __align__(16) short As[4096];
    __shared__ __align__(16) short Bs[4096];

    const int tid  = threadIdx.x;
    const int lane = tid & 63;
    const int w    = tid >> 6;
    const int wm   = w >> 1, wn = w & 1;
    const int lr   = lane & 15;
    const int lkc  = lane >> 4;

    const int bx = blockIdx.x;
    const int m0 = (bx / nblk) * 128;
    const int n0 = (bx % nblk) * 128;

    const int fa = 2 * w;
    const size_t aoff0 = (size_t)(m0 + fa * 16 + lr) * K + lkc * 8;
    const size_t aoff1 = aoff0 + (size_t)16 * K;
    const size_t boff0 = (size_t)(n0 + fa * 16 + lr) * K + lkc * 8;
    const size_t boff1 = boff0 + (size_t)16 * K;

    floatx4 acc[4][4];
#pragma unroll
    for (int i = 0; i < 4; ++i)
#pragma unroll
        for (int j = 0; j < 4; ++j) acc[i][j] = floatx4{0.f, 0.f, 0.f, 0.f};

#pragma unroll 1
    for (int ph = 0; ph < NPH; ++ph) {
        const __hip_bfloat16* Ap = (ph == 2) ? Alo : Ahi;
        const __hip_bfloat16* Bp = (ph == 1) ? Blo : Bhi;

        short8_t ra0 = *(const short8_t*)(const void*)(Ap + aoff0);
        short8_t ra1 = *(const short8_t*)(const void*)(Ap + aoff1);
        short8_t rb0 = *(const short8_t*)(const void*)(Bp + boff0);
        short8_t rb1 = *(const short8_t*)(const void*)(Bp + boff1);

        for (int k0 = 0; k0 < K; k0 += 32) {
            __syncthreads();
            *(short8_t*)(void*)&As[(fa    ) * 512 + lane * 8] = ra0;
            *(short8_t*)(void*)&As[(fa + 1) * 512 + lane * 8] = ra1;
            *(short8_t*)(void*)&Bs[(fa    ) * 512 + lane * 8] = rb0;
            *(short8_t*)(void*)&Bs[(fa + 1) * 512 + lane * 8] = rb1;
            __syncthreads();

            if (k0 + 32 < K) {
                int kn = k0 + 32;
                ra0 = *(const short8_t*)(const void*)(Ap + aoff0 + kn);
                ra1 = *(const short8_t*)(const void*)(Ap + aoff1 + kn);
                rb0 = *(const short8_t*)(const void*)(Bp + boff0 + kn);
                rb1 = *(const short8_t*)(const void*)(Bp + boff1 + kn);
            }

            short8_t af[4], bf[4];
#pragma unroll
            for (int i = 0; i < 4; ++i)
                af[i] = *(const short8_t*)(const void*)&As[(wm * 4 + i) * 512 + lane * 8];
#pragma unroll
            for (int j = 0; j < 4; ++j)
                bf[j] = *(const short8_t*)(const void*)&Bs[(wn * 4 + j) * 512 + lane * 8];
#pragma unroll
            for (int i = 0; i < 4; ++i)
#pragma unroll
                for (int j = 0; j < 4; ++j)
                    acc[i][j] = __builtin_amdgcn_mfma_f32_16x16x32_bf16(af[i], bf[j], acc[i][j], 0, 0, 0);
        }
    }

    // C/D layout (m89-verified): col=lane&15, row=(lane>>4)*4+r
#pragma unroll
    for (int i = 0; i < 4; ++i) {
        const int row = m0 + wm * 64 + i * 16 + (lane >> 4) * 4;
#pragma unroll
        for (int j = 0; j < 4; ++j) {
            const int col = n0 + wn * 64 + j * 16 + (lane & 15);
            if (col < Nreal) {
                float bv = bias ? bias[col] : 0.0f;
#pragma unroll
                for (int r = 0; r < 4; ++r) {
                    float v = acc[i][j][r] + bv;
                    if (EPI == 1) v = (col < 128) ? sigmoidf_(v) : tanhf(v);
                    size_t o = (size_t)(row + r) * Nreal + col;
                    if (OUTMODE == 0) {
                        if (ACCUM) v += Cf[o];
                        Cf[o] = v;
                    } else {
                        __hip_bfloat16 h, l;
                        bsplit_(v, h, l);
                        Chi[o] = h; Clo[o] = l;
                    }
                }
            }
        }
    }
}

// ---------------------------------------------------------------------------
// fp32 tiled GEMM (PP = ini_embd @ W2 only)
// ---------------------------------------------------------------------------
template<int BM, int BN, int BK, int TM, int TN>
__global__ __launch_bounds__(256)
void k_gemm(const float* __restrict__ A, const float* __restrict__ B,
            float* __restrict__ C, int M, int N, int K)
{
    __shared__ float As[BK][BM + 4];
    __shared__ float Bs[BK][BN + 4];
    const int tid = threadIdx.y * blockDim.x + threadIdx.x;
    const int m0 = blockIdx.y * BM;
    const int n0 = blockIdx.x * BN;
    float acc[TM][TN];
#pragma unroll
    for (int i = 0; i < TM; ++i)
#pragma unroll
        for (int j = 0; j < TN; ++j) acc[i][j] = 0.0f;
    for (int k0 = 0; k0 < K; k0 += BK) {
#pragma unroll
        for (int i = tid; i < BM * BK; i += 256) {
            int r = i / BK, c = i % BK;
            int m = m0 + r;
            As[c][r] = (m < M) ? A[(size_t)m * K + k0 + c] : 0.0f;
        }
#pragma unroll
        for (int i = tid; i < BK * BN; i += 256) {
            int r = i / BN, c = i % BN;
            Bs[r][c] = B[(size_t)(k0 + r) * N + n0 + c];
        }
        __syncthreads();
#pragma unroll
        for (int kk = 0; kk < BK; ++kk) {
            float a[TM], b[TN];
#pragma unroll
            for (int i = 0; i < TM; ++i) a[i] = As[kk][threadIdx.y * TM + i];
#pragma unroll
            for (int j = 0; j < TN; ++j) b[j] = Bs[kk][threadIdx.x * TN + j];
#pragma unroll
            for (int i = 0; i < TM; ++i)
#pragma unroll
                for (int j = 0; j < TN; ++j) acc[i][j] += a[i] * b[j];
        }
        __syncthreads();
    }
#pragma unroll
    for (int i = 0; i < TM; ++i) {
        int m = m0 + threadIdx.y * TM + i;
        if (m >= M) continue;
#pragma unroll
        for (int j = 0; j < TN; ++j)
            C[(size_t)m * N + n0 + threadIdx.x * TN + j] = acc[i][j];
    }
}

// ---------------------------------------------------------------------------
// Pack / convert / split kernels
// ---------------------------------------------------------------------------
__global__ void k_pack_w2(const float* __restrict__ Wa_w, float* __restrict__ W2)
{
    int idx = blockIdx.x * blockDim.x + threadIdx.x;
    if (idx >= E_ * 2 * A_) return;
    int e = idx / (2 * A_), j = idx % (2 * A_);
    W2[idx] = (j < A_) ? Wa_w[(size_t)e * A_ + j]
                       : Wa_w[(size_t)(E_ + e) * A_ + (j - A_)];
}

__global__ void k_weaT_split(const float* __restrict__ erase_w, const float* __restrict__ add_w,
                             const float* __restrict__ erase_b, const float* __restrict__ add_b,
                             __hip_bfloat16* __restrict__ Whi, __hip_bfloat16* __restrict__ Wlo,
                             float* __restrict__ bea)
{
    int idx = blockIdx.x * blockDim.x + threadIdx.x;
    if (idx < 256 * 256) {
        int n = idx / 256, k = idx % 256;
        float v = (n < V_) ? erase_w[(size_t)k * V_ + n] : add_w[(size_t)k * V_ + (n - V_)];
        bsplit_(v, Whi[idx], Wlo[idx]);
    }
    if (idx < 2 * V_) bea[idx] = (idx < V_) ? erase_b[idx] : add_b[idx - V_];
}

__global__ void k_wih_split(const float* __restrict__ Wih,
                            __hip_bfloat16* __restrict__ hi, __hip_bfloat16* __restrict__ lo)
{
    int idx = blockIdx.x * blockDim.x + threadIdx.x;
    if (idx < 768 * 256) bsplit_(Wih[idx], hi[idx], lo[idx]);
}

__global__ void k_tranHT_split(const float* __restrict__ tranH_w,
                               __hip_bfloat16* __restrict__ hi, __hip_bfloat16* __restrict__ lo)
{
    int idx = blockIdx.x * blockDim.x + threadIdx.x;
    if (idx >= 256 * 320) return;
    int n = idx / 320, k = idx % 320;
    bsplit_(tranH_w[(size_t)k * 256 + n], hi[idx], lo[idx]);
}

__global__ void k_outWT_split(const float* __restrict__ out_w,
                              __hip_bfloat16* __restrict__ hi, __hip_bfloat16* __restrict__ lo)
{
    int idx = blockIdx.x * blockDim.x + threadIdx.x;
    if (idx >= 2048 * 448) return;
    int n = idx / 448, k = idx % 448;
    float v = (n < D_) ? out_w[(size_t)k * D_ + n] : 0.0f;
    bsplit_(v, hi[idx], lo[idx]);
}

__global__ void k_km_split(const float* __restrict__ ini_embd, const int* __restrict__ KMIds,
                           __hip_bfloat16* __restrict__ hi, __hip_bfloat16* __restrict__ lo)
{
    int idx = blockIdx.x * blockDim.x + threadIdx.x;
    if (idx >= S_ * E_) return;
    int s = idx / E_, k = idx % E_;
    bsplit_(ini_embd[(size_t)KMIds[s] * E_ + k], hi[idx], lo[idx]);
}

__global__ void k_embMT_chunk(const float* __restrict__ embG, const int* __restrict__ mapInfo,
                              int c, __hip_bfloat16* __restrict__ hi, __hip_bfloat16* __restrict__ lo)
{
    int idx = blockIdx.x * blockDim.x + threadIdx.x;
    if (idx >= 256 * 1024) return;
    int e = idx >> 10, dd = idx & 1023;
    int d = c * 1024 + dd;
    float v = (d < D_) ? embG[(size_t)mapInfo[d] * E_ + e] : 0.0f;
    bsplit_(v, hi[idx], lo[idx]);
}

__global__ void k_x_chunk(const float* __restrict__ X, int c,
                          __hip_bfloat16* __restrict__ hi, __hip_bfloat16* __restrict__ lo)
{
    int idx = blockIdx.x * blockDim.x + threadIdx.x;
    if (idx >= M_ * 1024) return;
    int m = idx >> 10, dd = idx & 1023;
    int d = c * 1024 + dd;
    float v = (d < D_) ? X[(size_t)m * D_ + d] : 0.0f;
    bsplit_(v, hi[idx], lo[idx]);
}

__global__ void k_split_flat(const float* __restrict__ src, int n,
                             __hip_bfloat16* __restrict__ hi, __hip_bfloat16* __restrict__ lo)
{
    int idx = blockIdx.x * blockDim.x + threadIdx.x;
    if (idx < n) bsplit_(src[idx], hi[idx], lo[idx]);
}

// Whh[j][e] f32 -> W4[e4][j][4] f32  (thread j reads float4 of its 4 e's; coalesced)
__global__ void k_wpk4(const float* __restrict__ Whh, float* __restrict__ W4)
{
    int idx = blockIdx.x * blockDim.x + threadIdx.x;
    if (idx >= 768 * 256) return;
    int j = idx / 256, e = idx % 256;
    int e4 = e >> 2, i = e & 3;
    W4[((size_t)e4 * 768 + j) * 4 + i] = Whh[idx];
}

__global__ void k_prof(const float* __restrict__ profiles, const float* __restrict__ emP_w,
                       const float* __restrict__ emP_b, float* __restrict__ prof)
{
    int b = blockIdx.x, j = threadIdx.x;
    float acc = emP_b[j];
    for (int k = 0; k < PS_; ++k) acc += profiles[(size_t)b * PS_ + k] * emP_w[(size_t)k * PE_ + j];
    prof[(size_t)b * PE_ + j] = acc;
}

__global__ void k_fill_tp(const float* __restrict__ prof,
                          __hip_bfloat16* __restrict__ At_hi, __hip_bfloat16* __restrict__ At_lo)
{
    int idx = blockIdx.x * blockDim.x + threadIdx.x;
    if (idx >= M_ * PE_) return;
    int m = idx >> 6, pe = idx & 63;
    float v = prof[(size_t)(m & (B_ - 1)) * PE_ + pe];
    size_t o = (size_t)m * 320 + 256 + pe;
    bsplit_(v, At_hi[o], At_lo[o]);
}

// ---------------------------------------------------------------------------
// GRAM group attention
// ---------------------------------------------------------------------------
__global__ void k_group_embed(const float* __restrict__ PP, const float* __restrict__ Wa_b,
                              const float* __restrict__ Ua_w, const float* __restrict__ ini_embd,
                              const int* __restrict__ leaves1, const int* __restrict__ anc1,
                              const int* __restrict__ leaves2, const int* __restrict__ anc2,
                              float* __restrict__ embedG)
{
    int n = blockIdx.x;
    int lane = threadIdx.x;
    const int* lv; const int* ac; int L;
    if (n < G1N_) { L = G1L_; lv = leaves1 + (size_t)n * G1L_; ac = anc1 + (size_t)n * G1L_; }
    else { int n2 = n - G1N_; L = G2L_; lv = leaves2 + (size_t)n2 * G2L_; ac = anc2 + (size_t)n2 * G2L_; }

    float score[6]; int ai[6];
    for (int l = 0; l < L; ++l) {
        int li = lv[l]; int av = ac[l]; ai[l] = av;
        float s = 0.0f;
        for (int a = lane; a < A_; a += 64) {
            float hv = tanhf(PP[(size_t)li * 256 + a] + PP[(size_t)av * 256 + 128 + a] + Wa_b[a]);
            s += hv * Ua_w[a];
        }
        for (int o = 32; o; o >>= 1) s += __shfl_xor(s, o);
        score[l] = s;
    }
    float mx = -1e30f;
    for (int l = 0; l < L; ++l) mx = fmaxf(mx, score[l]);
    float w[6], sum = 0.0f;
    for (int l = 0; l < L; ++l) { w[l] = __expf(score[l] - mx); sum += w[l]; }
    float inv = 1.0f / sum;
    for (int e = lane; e < E_; e += 64) {
        float acc = 0.0f;
        for (int l = 0; l < L; ++l) acc += w[l] * inv * ini_embd[(size_t)ai[l] * E_ + e];
        embedG[(size_t)n * E_ + e] = acc;
    }
}

// ---------------------------------------------------------------------------
// GRU scan v3: 64 wgs x 768 threads (12 waves), 4 samples/wg.
// f32 weights W4[e4][768][4]: one coalesced float4/thread per 4-e chunk;
// L2-resident regime (8 wgs/XCD, same as proven round-3 layout).
// h fp32 in LDS, broadcast float4 reads. Gate exchange via LDS.
// ---------------------------------------------------------------------------
__global__ __launch_bounds__(768)
void k_gru3(const float* __restrict__ gx, const float* __restrict__ W4,
            const float* __restrict__ bhh, const int* __restrict__ X_len,
            float* __restrict__ gruo,
            __hip_bfloat16* __restrict__ At_hi, __hip_bfloat16* __restrict__ At_lo)
{
    const int wg = blockIdx.x, s0 = wg * 4, tid = threadIdx.x;
    __shared__ float hS[4][H_];        // 4 KB
    __shared__ float ghS[4][768];      // 12 KB
    __shared__ float gxnS[4][H_];      // 4 KB

    for (int i = tid; i < 4 * H_; i += 768) ((float*)hS)[i] = 0.0f;
    const int len0 = X_len[s0], len1 = X_len[s0 + 1], len2 = X_len[s0 + 2], len3 = X_len[s0 + 3];
    __syncthreads();

    const float bj = bhh[tid];
    const float4* Wv = (const float4*)W4;

    for (int t = 0; t < T_; ++t) {
        const size_t gb = ((size_t)t * B_ + s0) * 768;
        float g0 = gx[gb + tid];
        float g1 = gx[gb + 768 + tid];
        float g2 = gx[gb + 1536 + tid];
        float g3 = gx[gb + 2304 + tid];

        float a0 = bj, a1 = bj, a2 = bj, a3 = bj;
#pragma unroll 8
        for (int e4 = 0; e4 < 64; ++e4) {
            float4 w = Wv[(size_t)e4 * 768 + tid];
            float4 h0 = *(const float4*)&hS[0][e4 * 4];
            float4 h1 = *(const float4*)&hS[1][e4 * 4];
            float4 h2 = *(const float4*)&hS[2][e4 * 4];
            float4 h3 = *(const float4*)&hS[3][e4 * 4];
            a0 += w.x * h0.x + w.y * h0.y + w.z * h0.z + w.w * h0.w;
            a1 += w.x * h1.x + w.y * h1.y + w.z * h1.z + w.w * h1.w;
            a2 += w.x * h2.x + w.y * h2.y + w.z * h2.z + w.w * h2.w;
            a3 += w.x * h3.x + w.y * h3.y + w.z * h3.z + w.w * h3.w;
        }

        __syncthreads();   // hS reads done before gate phase overwrites hS
        if (tid < 512) {
            ghS[0][tid] = a0 + g0; ghS[1][tid] = a1 + g1;
            ghS[2][tid] = a2 + g2; ghS[3][tid] = a3 + g3;
        } else {
            ghS[0][tid] = a0; ghS[1][tid] = a1; ghS[2][tid] = a2; ghS[3][tid] = a3;
            gxnS[0][tid - 512] = g0; gxnS[1][tid - 512] = g1;
            gxnS[2][tid - 512] = g2; gxnS[3][tid - 512] = g3;
        }
        __syncthreads();

        if (tid < H_) {
            const int hj = tid;
#pragma unroll
            for (int s = 0; s < 4; ++s) {
                int len = (s == 0) ? len0 : (s == 1) ? len1 : (s == 2) ? len2 : len3;
                float r  = sigmoidf_(ghS[s][hj]);
                float z  = sigmoidf_(ghS[s][256 + hj]);
                float nn = tanhf(gxnS[s][hj] + r * ghS[s][512 + hj]);
                float hold = hS[s][hj];
                float hnew = (1.0f - z) * nn + z * hold;
                bool msk = (t < len);
                float hv = msk ? hnew : hold;
                hS[s][hj] = hv;
                float ov = msk ? hv : 0.0f;
                size_t m = (size_t)t * B_ + (s0 + s);
                gruo[m * H_ + hj] = ov;
                size_t o = m * 320 + hj;
                bsplit_(ov, At_hi[o], At_lo[o]);
            }
        }
        __syncthreads();
    }
}

// ---------------------------------------------------------------------------
// Value-memory scan
// ---------------------------------------------------------------------------
__global__ __launch_bounds__(256)
void k_mem(const float* __restrict__ slotw, const float* __restrict__ era,
           const float* __restrict__ iniVam, float* __restrict__ readv)
{
    const int b = blockIdx.x;
    const int tid = threadIdx.x;
    const int v = tid & (V_ - 1);
    const int sh = tid >> 7;
    const int sbase = sh * 64;

    float VM[64];
#pragma unroll 8
    for (int i = 0; i < 64; ++i) VM[i] = iniVam[(size_t)(sbase + i) * V_ + v];

    __shared__ float swL[S_];
    __shared__ float eaL[2 * V_];
    __shared__ float part[V_];

    for (int t = 0; t < T_; ++t) {
        size_t m = (size_t)t * B_ + b;
        if (tid < S_) swL[tid] = slotw[m * S_ + tid];
        eaL[tid] = era[m * (2 * V_) + tid];
        __syncthreads();

        float er = eaL[v], ad = eaL[V_ + v];
        float acc = 0.0f;
#pragma unroll 8
        for (int i = 0; i < 64; ++i) {
            float sv = swL[sbase + i];
            float vm = VM[i];
            acc += sv * vm;
            VM[i] = vm * (1.0f - sv * er) + sv * ad;
        }
        if (sh == 1) part[v] = acc;
        __syncthreads();
        if (sh == 0) readv[m * V_ + v] = acc + part[v];
        __syncthreads();
    }
}

// ---------------------------------------------------------------------------
// F = [gruo | read | prof2] as bf16 split planes
// ---------------------------------------------------------------------------
__global__ __launch_bounds__(256)
void k_build_final(const float* __restrict__ gruo, const float* __restrict__ readv,
                   const float* __restrict__ prof, const float* __restrict__ attnP_w,
                   const float* __restrict__ attnP_b,
                   __hip_bfloat16* __restrict__ F_hi, __hip_bfloat16* __restrict__ F_lo)
{
    const int m = blockIdx.x;
    const int b = m & (B_ - 1);
    const int tid = threadIdx.x;
    __shared__ float rd[V_];
    __shared__ float pf[PE_];
    if (tid < V_) rd[tid] = readv[(size_t)m * V_ + tid];
    if (tid < PE_) pf[tid] = prof[(size_t)b * PE_ + tid];
    __syncthreads();

    size_t base = (size_t)m * KF_;
    bsplit_(gruo[(size_t)m * H_ + tid], F_hi[base + tid], F_lo[base + tid]);
    if (tid < V_) bsplit_(rd[tid], F_hi[base + H_ + tid], F_lo[base + H_ + tid]);
    if (tid < PE_) {
        float a = attnP_b[tid];
        for (int k = 0; k < PE_; ++k) a += pf[k] * attnP_w[(size_t)k * PE_ + tid];
        for (int k = 0; k < V_; ++k) a += rd[k] * attnP_w[(size_t)(PE_ + k) * PE_ + tid];
        a = fmaxf(a, 0.0f);
        bsplit_(pf[tid] * a, F_hi[base + H_ + V_ + tid], F_lo[base + H_ + V_ + tid]);
    }
}

// ---------------------------------------------------------------------------
// Softmaxes
// ---------------------------------------------------------------------------
__global__ void k_softmax128(float* __restrict__ C)
{
    const int m = blockIdx.x;
    const size_t base = (size_t)m * S_;
    const int lane = threadIdx.x;
    float a = C[base + lane], b = C[base + 64 + lane];
    float mx = fmaxf(a, b);
    for (int o = 32; o; o >>= 1) mx = fmaxf(mx, __shfl_xor(mx, o));
    float e0 = __expf(a - mx), e1 = __expf(b - mx);
    float s = e0 + e1;
    for (int o = 32; o; o >>= 1) s += __shfl_xor(s, o);
    float inv = 1.0f / s;
    C[base + lane] = e0 * inv;
    C[base + 64 + lane] = e1 * inv;
}

__global__ __launch_bounds__(256)
void k_softmax2000(float* __restrict__ C)
{
    const int m = blockIdx.x;
    const size_t base = (size_t)m * D_;
    const int tid = threadIdx.x;
    const int wid = tid >> 6, lane = tid & 63;
    __shared__ float red[4], red2[4];

    float v[8];
#pragma unroll
    for (int i = 0; i < 8; ++i) {
        int d = i * 256 + tid;
        v[i] = (d < D_) ? C[base + d] : -1e30f;
    }
    float mx = v[0];
#pragma unroll
    for (int i = 1; i < 8; ++i) mx = fmaxf(mx, v[i]);
    for (int o = 32; o; o >>= 1) mx = fmaxf(mx, __shfl_xor(mx, o));
    if (lane == 0) red[wid] = mx;
    __syncthreads();
    mx = fmaxf(fmaxf(red[0], red[1]), fmaxf(red[2], red[3]));

    float sum = 0.0f;
#pragma unroll
    for (int i = 0; i < 8; ++i) { v[i] = __expf(v[i] - mx); sum += v[i]; }
    for (int o = 32; o; o >>= 1) sum += __shfl_xor(sum, o);
    if (lane == 0) red2[wid] = sum;
    __syncthreads();
    sum = red2[0] + red2[1] + red2[2] + red2[3];
    float inv = 1.0f / sum;
#pragma unroll
    for (int i = 0; i < 8; ++i) {
        int d = i * 256 + tid;
        if (d < D_) C[base + d] = v[i] * inv;
    }
}

// ---------------------------------------------------------------------------
// Launch
// ---------------------------------------------------------------------------
extern "C" void kernel_launch(void* const* d_in, const int* in_sizes, int n_in,
                              void* d_out, int out_size, void* d_ws, size_t ws_size,
                              hipStream_t stream)
{
    const float* X        = (const float*)d_in[0];
    const float* profiles = (const float*)d_in[1];
    const float* ini_embd = (const float*)d_in[2];
    const float* Wa_w     = (const float*)d_in[3];
    const float* Wa_b     = (const float*)d_in[4];
    const float* Ua_w     = (const float*)d_in[5];
    const float* gru_Wih  = (const float*)d_in[6];
    const float* gru_Whh  = (const float*)d_in[7];
    const float* gru_bih  = (const float*)d_in[8];
    const float* gru_bhh  = (const float*)d_in[9];
    const float* tranH_w  = (const float*)d_in[10];
    const float* tranH_b  = (const float*)d_in[11];
    const float* out_w    = (const float*)d_in[12];
    const float* out_b    = (const float*)d_in[13];
    const float* erase_w  = (const float*)d_in[14];
    const float* erase_b  = (const float*)d_in[15];
    const float* add_w    = (const float*)d_in[16];
    const float* add_b    = (const float*)d_in[17];
    const float* iniVam   = (const float*)d_in[18];
    const float* emP_w    = (const float*)d_in[19];
    const float* emP_b    = (const float*)d_in[20];
    const float* attnP_w  = (const float*)d_in[21];
    const float* attnP_b  = (const float*)d_in[22];
    const int* KMIds   = (const int*)d_in[23];
    const int* leaves1 = (const int*)d_in[24];
    const int* anc1    = (const int*)d_in[25];
    const int* leaves2 = (const int*)d_in[26];
    const int* anc2    = (const int*)d_in[27];
    const int* mapInfo = (const int*)d_in[28];
    const int* X_len   = (const int*)d_in[29];

    char* ws = (char*)d_ws;
    float* out = (float*)d_out;
    typedef __hip_bfloat16 bf16;

    // ---- workspace layout (bytes) ----
    const size_t R0 = 0;            // 67,108,864 multi-use region
    const size_t R1 = 67108864;     // 16,777,216 : Xe f32; later gruo f32
    const size_t R2 = 83886080;     // 16,777,216 : era f32
    const size_t R3 = 100663296;    // 20,971,520 : At_hi/At_lo; later slotw/readv
    size_t P = 121634816;
    const size_t E0HI = P; P += 524288;
    const size_t E0LO = P; P += 524288;
    const size_t E1HI = P; P += 524288;
    const size_t E1LO = P; P += 524288;
    const size_t OWHI = P; P += 1835008;
    const size_t OWLO = P; P += 1835008;
    const size_t WIHI = P; P += 393216;
    const size_t WILO = P; P += 393216;
    const size_t WEHI = P; P += 131072;
    const size_t WELO = P; P += 131072;
    const size_t THHI = P; P += 163840;
    const size_t THLO = P; P += 163840;
    const size_t KMHI = P; P += 65536;
    const size_t KMLO = P; P += 65536;
    const size_t W4O  = P; P += 786432;   // Whh f32 [64][768][4]
    const size_t PROF = P; P += 65536;
    const size_t BEA  = P; P += 1024;
    const size_t W2O  = P; P += 262144;

    float* PP      = (float*)(ws + R0);
    float* embG    = (float*)(ws + R0 + 12288000);
    bf16*  Xc_hi   = (bf16*)(ws + R0);
    bf16*  Xc_lo   = (bf16*)(ws + R0 + 33554432);
    float* gx      = (float*)(ws + R0);
    bf16*  Xe_hi   = (bf16*)(ws + R0 + 50331648);
    bf16*  Xe_lo   = (bf16*)(ws + R0 + 58720256);
    bf16*  tran_hi = (bf16*)(ws + R0);
    bf16*  tran_lo = (bf16*)(ws + R0 + 8388608);
    bf16*  F_hi    = (bf16*)(ws + R0);
    bf16*  F_lo    = (bf16*)(ws + R0 + 14680064);
    float* Xe_f    = (float*)(ws + R1);
    float* gruo    = (float*)(ws + R1);
    float* era     = (float*)(ws + R2);
    bf16*  At_hi   = (bf16*)(ws + R3);
    bf16*  At_lo   = (bf16*)(ws + R3 + 10485760);
    float* slotw   = (float*)(ws + R3);
    float* readv   = (float*)(ws + R3 + 10485760);
    bf16*  E0hi = (bf16*)(ws + E0HI); bf16* E0lo = (bf16*)(ws + E0LO);
    bf16*  E1hi = (bf16*)(ws + E1HI); bf16* E1lo = (bf16*)(ws + E1LO);
    bf16*  OWhi = (bf16*)(ws + OWHI); bf16* OWlo = (bf16*)(ws + OWLO);
    bf16*  WIhi = (bf16*)(ws + WIHI); bf16* WIlo = (bf16*)(ws + WILO);
    bf16*  WEhi = (bf16*)(ws + WEHI); bf16* WElo = (bf16*)(ws + WELO);
    bf16*  THhi = (bf16*)(ws + THHI); bf16* THlo = (bf16*)(ws + THLO);
    bf16*  KMhi = (bf16*)(ws + KMHI); bf16* KMlo = (bf16*)(ws + KMLO);
    float* W4   = (float*)(ws + W4O);
    float* prof = (float*)(ws + PROF);
    float* bea  = (float*)(ws + BEA);
    float* W2p  = (float*)(ws + W2O);

    // ---- weight packs ----
    k_pack_w2<<<(E_ * 2 * A_ + 255) / 256, 256, 0, stream>>>(Wa_w, W2p);
    k_weaT_split<<<(256 * 256 + 255) / 256, 256, 0, stream>>>(erase_w, add_w, erase_b, add_b, WEhi, WElo, bea);
    k_wih_split<<<(768 * 256 + 255) / 256, 256, 0, stream>>>(gru_Wih, WIhi, WIlo);
    k_tranHT_split<<<(256 * 320 + 255) / 256, 256, 0, stream>>>(tranH_w, THhi, THlo);
    k_outWT_split<<<(2048 * 448 + 255) / 256, 256, 0, stream>>>(out_w, OWhi, OWlo);
    k_km_split<<<(S_ * E_ + 255) / 256, 256, 0, stream>>>(ini_embd, KMIds, KMhi, KMlo);
    k_wpk4<<<(768 * 256 + 255) / 256, 256, 0, stream>>>(gru_Whh, W4);
    k_prof<<<B_, PE_, 0, stream>>>(profiles, emP_w, emP_b, prof);

    // ---- ontology attention -> embedMat ----
    {
        dim3 blk(16, 16);
        dim3 grid(4, (TN_ + 63) / 64);
        k_gemm<64, 64, 16, 4, 4><<<grid, blk, 0, stream>>>(ini_embd, W2p, PP, TN_, 256, E_);
    }
    k_group_embed<<<G1N_ + G2N_, 64, 0, stream>>>(PP, Wa_b, Ua_w, ini_embd,
                                                  leaves1, anc1, leaves2, anc2, embG);
    k_embMT_chunk<<<(256 * 1024) / 256, 256, 0, stream>>>(embG, mapInfo, 0, E0hi, E0lo);
    k_embMT_chunk<<<(256 * 1024) / 256, 256, 0, stream>>>(embG, mapInfo, 1, E1hi, E1lo);

    // ---- Xe = X @ embM (split, K-chunked, fp32 accumulate) ----
    k_x_chunk<<<(M_ * 1024) / 256, 256, 0, stream>>>(X, 0, Xc_hi, Xc_lo);
    k_mgemm3<0, false, 0, 3><<<128 * 2, 256, 0, stream>>>(Xc_hi, Xc_lo, E0hi, E0lo,
        nullptr, Xe_f, nullptr, nullptr, 1024, 256, 2);
    k_x_chunk<<<(M_ * 1024) / 256, 256, 0, stream>>>(X, 1, Xc_hi, Xc_lo);
    k_mgemm3<0, true, 0, 3><<<128 * 2, 256, 0, stream>>>(Xc_hi, Xc_lo, E1hi, E1lo,
        nullptr, Xe_f, nullptr, nullptr, 1024, 256, 2);

    k_split_flat<<<(M_ * 256) / 256, 256, 0, stream>>>(Xe_f, M_ * 256, Xe_hi, Xe_lo);

    // ---- era = gates(Xe @ Wea + bea) ----
    k_mgemm3<1, false, 0, 3><<<128 * 2, 256, 0, stream>>>(Xe_hi, Xe_lo, WEhi, WElo,
        bea, era, nullptr, nullptr, 256, 256, 2);

    // ---- gx = Xe @ Wih^T + bih ----
    k_mgemm3<0, false, 0, 3><<<128 * 6, 256, 0, stream>>>(Xe_hi, Xe_lo, WIhi, WIlo,
        gru_bih, gx, nullptr, nullptr, 256, 768, 6);

    // ---- GRU scan v3 ----
    k_gru3<<<64, 768, 0, stream>>>(gx, W4, gru_bhh, X_len, gruo, At_hi, At_lo);
    k_fill_tp<<<(M_ * PE_) / 256, 256, 0, stream>>>(prof, At_hi, At_lo);

    // ---- tran = [gruo|prof] @ tranH + b ----
    k_mgemm3<0, false, 1, 3><<<128 * 2, 256, 0, stream>>>(At_hi, At_lo, THhi, THlo,
        tranH_b, nullptr, tran_hi, tran_lo, 320, 256, 2);

    // ---- slot logits = tran @ KM^T ----
    k_mgemm3<0, false, 0, 3><<<128 * 1, 256, 0, stream>>>(tran_hi, tran_lo, KMhi, KMlo,
        nullptr, slotw, nullptr, nullptr, 256, 128, 1);

    k_softmax128<<<M_, 64, 0, stream>>>(slotw);
    k_mem<<<B_, 256, 0, stream>>>(slotw, era, iniVam, readv);
    k_build_final<<<M_, 256, 0, stream>>>(gruo, readv, prof, attnP_w, attnP_b, F_hi, F_lo);

    // ---- logits = F @ out_w + out_b (1-phase bf16) ----
    k_mgemm3<0, false, 0, 1><<<128 * 16, 256, 0, stream>>>(F_hi, F_lo, OWhi, OWlo,
        out_b, out, nullptr, nullptr, 448, 2000, 16);

    k_softmax2000<<<M_, 256, 0, stream>>>(out);
}

// Round 6
// 1094.315 us; speedup vs baseline: 2.8304x; 1.4830x over previous
//
#include <hip/hip_runtime.h>
#include <hip/hip_bf16.h>
#include <cmath>

#define T_  64
#define B_  256
#define D_  2000
#define TN_ 3000
#define E_  256
#define H_  256
#define A_  128
#define V_  128
#define PS_ 64
#define PE_ 64
#define S_  128
#define G1N_ 1500
#define G1L_ 4
#define G2N_ 1500
#define G2L_ 6
#define M_  (T_ * B_)
#define KF_ (H_ + V_ + PE_)

typedef __attribute__((ext_vector_type(8))) short short8_t;
typedef __attribute__((ext_vector_type(4))) float floatx4;
typedef _Float16 __attribute__((ext_vector_type(2))) h2_t;
typedef _Float16 __attribute__((ext_vector_type(8))) h8_t;

static __device__ __forceinline__ float sigmoidf_(float x) {
    return 1.0f / (1.0f + __expf(-x));
}

static __device__ __forceinline__ void bsplit_(float v, __hip_bfloat16& hi, __hip_bfloat16& lo) {
    hi = __float2bfloat16(v);
    lo = __float2bfloat16(v - __bfloat162float(hi));
}

static __device__ __forceinline__ float dot2_(unsigned int w, unsigned int h, float acc) {
    union { unsigned int u; h2_t h; } cw, ch;
    cw.u = w; ch.u = h;
#if __has_builtin(__builtin_amdgcn_fdot2)
    return __builtin_amdgcn_fdot2(cw.h, ch.h, acc, false);
#else
    return acc + (float)cw.h[0] * (float)ch.h[0] + (float)cw.h[1] * (float)ch.h[1];
#endif
}

template<int DT>
static __device__ __forceinline__ floatx4 mfma16_(short8_t a, short8_t b, floatx4 c) {
    if constexpr (DT == 0) {
        return __builtin_amdgcn_mfma_f32_16x16x32_bf16(a, b, c, 0, 0, 0);
    } else {
        union { short8_t s; h8_t h; } ua, ub;
        ua.s = a; ub.s = b;
        return __builtin_amdgcn_mfma_f32_16x16x32_f16(ua.h, ub.h, c, 0, 0, 0);
    }
}

// ---------------------------------------------------------------------------
// Split MFMA GEMM: C = A @ B. DT=0: bf16 planes (NPH=3 -> fp32-grade).
// DT=1: f16 planes, NPH must be 1 (f16 hi-only, ~2^-12 accurate).
// B given as BT[Npad][K] row-major. M mult 128, K mult 32, Npad = nblk*128.
// ---------------------------------------------------------------------------
template<int EPI, bool ACCUM, int OUTMODE, int NPH, int DT>
__global__ __launch_bounds__(256)
void k_mgemm3(const __hip_bfloat16* __restrict__ Ahi, const __hip_bfloat16* __restrict__ Alo,
              const __hip_bfloat16* __restrict__ Bhi, const __hip_bfloat16* __restrict__ Blo,
              const float* __restrict__ bias, float* __restrict__ Cf,
              __hip_bfloat16* __restrict__ Chi, __hip_bfloat16* __restrict__ Clo,
              int K, int Nreal, int nblk)
{
    __shared__ __align__(16) short As[4096];
    __shared__ __align__(16) short Bs[4096];

    const int tid  = threadIdx.x;
    const int lane = tid & 63;
    const int w    = tid >> 6;
    const int wm   = w >> 1, wn = w & 1;
    const int lr   = lane & 15;
    const int lkc  = lane >> 4;

    const int bx = blockIdx.x;
    const int m0 = (bx / nblk) * 128;
    const int n0 = (bx % nblk) * 128;

    const int fa = 2 * w;
    const size_t aoff0 = (size_t)(m0 + fa * 16 + lr) * K + lkc * 8;
    const size_t aoff1 = aoff0 + (size_t)16 * K;
    const size_t boff0 = (size_t)(n0 + fa * 16 + lr) * K + lkc * 8;
    const size_t boff1 = boff0 + (size_t)16 * K;

    floatx4 acc[4][4];
#pragma unroll
    for (int i = 0; i < 4; ++i)
#pragma unroll
        for (int j = 0; j < 4; ++j) acc[i][j] = floatx4{0.f, 0.f, 0.f, 0.f};

#pragma unroll 1
    for (int ph = 0; ph < NPH; ++ph) {
        const __hip_bfloat16* Ap = (ph == 2) ? Alo : Ahi;
        const __hip_bfloat16* Bp = (ph == 1) ? Blo : Bhi;

        short8_t ra0 = *(const short8_t*)(const void*)(Ap + aoff0);
        short8_t ra1 = *(const short8_t*)(const void*)(Ap + aoff1);
        short8_t rb0 = *(const short8_t*)(const void*)(Bp + boff0);
        short8_t rb1 = *(const short8_t*)(const void*)(Bp + boff1);

        for (int k0 = 0; k0 < K; k0 += 32) {
            __syncthreads();
            *(short8_t*)(void*)&As[(fa    ) * 512 + lane * 8] = ra0;
            *(short8_t*)(void*)&As[(fa + 1) * 512 + lane * 8] = ra1;
            *(short8_t*)(void*)&Bs[(fa    ) * 512 + lane * 8] = rb0;
            *(short8_t*)(void*)&Bs[(fa + 1) * 512 + lane * 8] = rb1;
            __syncthreads();

            if (k0 + 32 < K) {
                int kn = k0 + 32;
                ra0 = *(const short8_t*)(const void*)(Ap + aoff0 + kn);
                ra1 = *(const short8_t*)(const void*)(Ap + aoff1 + kn);
                rb0 = *(const short8_t*)(const void*)(Bp + boff0 + kn);
                rb1 = *(const short8_t*)(const void*)(Bp + boff1 + kn);
            }

            short8_t af[4], bf[4];
#pragma unroll
            for (int i = 0; i < 4; ++i)
                af[i] = *(const short8_t*)(const void*)&As[(wm * 4 + i) * 512 + lane * 8];
#pragma unroll
            for (int j = 0; j < 4; ++j)
                bf[j] = *(const short8_t*)(const void*)&Bs[(wn * 4 + j) * 512 + lane * 8];
#pragma unroll
            for (int i = 0; i < 4; ++i)
#pragma unroll
                for (int j = 0; j < 4; ++j)
                    acc[i][j] = mfma16_<DT>(af[i], bf[j], acc[i][j]);
        }
    }

    // C/D layout (m89-verified): col=lane&15, row=(lane>>4)*4+r
#pragma unroll
    for (int i = 0; i < 4; ++i) {
        const int row = m0 + wm * 64 + i * 16 + (lane >> 4) * 4;
#pragma unroll
        for (int j = 0; j < 4; ++j) {
            const int col = n0 + wn * 64 + j * 16 + (lane & 15);
            if (col < Nreal) {
                float bv = bias ? bias[col] : 0.0f;
#pragma unroll
                for (int r = 0; r < 4; ++r) {
                    float v = acc[i][j][r] + bv;
                    if (EPI == 1) v = (col < 128) ? sigmoidf_(v) : tanhf(v);
                    size_t o = (size_t)(row + r) * Nreal + col;
                    if (OUTMODE == 0) {
                        if (ACCUM) v += Cf[o];
                        Cf[o] = v;
                    } else {
                        __hip_bfloat16 h, l;
                        bsplit_(v, h, l);
                        Chi[o] = h; Clo[o] = l;
                    }
                }
            }
        }
    }
}

// ---------------------------------------------------------------------------
// fp32 tiled GEMM (PP = ini_embd @ W2 only)
// ---------------------------------------------------------------------------
template<int BM, int BN, int BK, int TM, int TN>
__global__ __launch_bounds__(256)
void k_gemm(const float* __restrict__ A, const float* __restrict__ B,
            float* __restrict__ C, int M, int N, int K)
{
    __shared__ float As[BK][BM + 4];
    __shared__ float Bs[BK][BN + 4];
    const int tid = threadIdx.y * blockDim.x + threadIdx.x;
    const int m0 = blockIdx.y * BM;
    const int n0 = blockIdx.x * BN;
    float acc[TM][TN];
#pragma unroll
    for (int i = 0; i < TM; ++i)
#pragma unroll
        for (int j = 0; j < TN; ++j) acc[i][j] = 0.0f;
    for (int k0 = 0; k0 < K; k0 += BK) {
#pragma unroll
        for (int i = tid; i < BM * BK; i += 256) {
            int r = i / BK, c = i % BK;
            int m = m0 + r;
            As[c][r] = (m < M) ? A[(size_t)m * K + k0 + c] : 0.0f;
        }
#pragma unroll
        for (int i = tid; i < BK * BN; i += 256) {
            int r = i / BN, c = i % BN;
            Bs[r][c] = B[(size_t)(k0 + r) * N + n0 + c];
        }
        __syncthreads();
#pragma unroll
        for (int kk = 0; kk < BK; ++kk) {
            float a[TM], b[TN];
#pragma unroll
            for (int i = 0; i < TM; ++i) a[i] = As[kk][threadIdx.y * TM + i];
#pragma unroll
            for (int j = 0; j < TN; ++j) b[j] = Bs[kk][threadIdx.x * TN + j];
#pragma unroll
            for (int i = 0; i < TM; ++i)
#pragma unroll
                for (int j = 0; j < TN; ++j) acc[i][j] += a[i] * b[j];
        }
        __syncthreads();
    }
#pragma unroll
    for (int i = 0; i < TM; ++i) {
        int m = m0 + threadIdx.y * TM + i;
        if (m >= M) continue;
#pragma unroll
        for (int j = 0; j < TN; ++j)
            C[(size_t)m * N + n0 + threadIdx.x * TN + j] = acc[i][j];
    }
}

// ---------------------------------------------------------------------------
// Pack / convert / split kernels
// ---------------------------------------------------------------------------
__global__ void k_pack_w2(const float* __restrict__ Wa_w, float* __restrict__ W2)
{
    int idx = blockIdx.x * blockDim.x + threadIdx.x;
    if (idx >= E_ * 2 * A_) return;
    int e = idx / (2 * A_), j = idx % (2 * A_);
    W2[idx] = (j < A_) ? Wa_w[(size_t)e * A_ + j]
                       : Wa_w[(size_t)(E_ + e) * A_ + (j - A_)];
}

__global__ void k_weaT_split(const float* __restrict__ erase_w, const float* __restrict__ add_w,
                             const float* __restrict__ erase_b, const float* __restrict__ add_b,
                             __hip_bfloat16* __restrict__ Whi, __hip_bfloat16* __restrict__ Wlo,
                             float* __restrict__ bea)
{
    int idx = blockIdx.x * blockDim.x + threadIdx.x;
    if (idx < 256 * 256) {
        int n = idx / 256, k = idx % 256;
        float v = (n < V_) ? erase_w[(size_t)k * V_ + n] : add_w[(size_t)k * V_ + (n - V_)];
        bsplit_(v, Whi[idx], Wlo[idx]);
    }
    if (idx < 2 * V_) bea[idx] = (idx < V_) ? erase_b[idx] : add_b[idx - V_];
}

__global__ void k_wih_split(const float* __restrict__ Wih,
                            __hip_bfloat16* __restrict__ hi, __hip_bfloat16* __restrict__ lo)
{
    int idx = blockIdx.x * blockDim.x + threadIdx.x;
    if (idx < 768 * 256) bsplit_(Wih[idx], hi[idx], lo[idx]);
}

__global__ void k_tranHT_split(const float* __restrict__ tranH_w,
                               __hip_bfloat16* __restrict__ hi, __hip_bfloat16* __restrict__ lo)
{
    int idx = blockIdx.x * blockDim.x + threadIdx.x;
    if (idx >= 256 * 320) return;
    int n = idx / 320, k = idx % 320;
    bsplit_(tranH_w[(size_t)k * 256 + n], hi[idx], lo[idx]);
}

// out_w transposed -> single f16 plane
__global__ void k_outWT_f16(const float* __restrict__ out_w, _Float16* __restrict__ dst)
{
    int idx = blockIdx.x * blockDim.x + threadIdx.x;
    if (idx >= 2048 * 448) return;
    int n = idx / 448, k = idx % 448;
    float v = (n < D_) ? out_w[(size_t)k * D_ + n] : 0.0f;
    dst[idx] = (_Float16)v;
}

__global__ void k_km_split(const float* __restrict__ ini_embd, const int* __restrict__ KMIds,
                           __hip_bfloat16* __restrict__ hi, __hip_bfloat16* __restrict__ lo)
{
    int idx = blockIdx.x * blockDim.x + threadIdx.x;
    if (idx >= S_ * E_) return;
    int s = idx / E_, k = idx % E_;
    bsplit_(ini_embd[(size_t)KMIds[s] * E_ + k], hi[idx], lo[idx]);
}

__global__ void k_embMT_chunk(const float* __restrict__ embG, const int* __restrict__ mapInfo,
                              int c, __hip_bfloat16* __restrict__ hi, __hip_bfloat16* __restrict__ lo)
{
    int idx = blockIdx.x * blockDim.x + threadIdx.x;
    if (idx >= 256 * 1024) return;
    int e = idx >> 10, dd = idx & 1023;
    int d = c * 1024 + dd;
    float v = (d < D_) ? embG[(size_t)mapInfo[d] * E_ + e] : 0.0f;
    bsplit_(v, hi[idx], lo[idx]);
}

__global__ void k_x_chunk(const float* __restrict__ X, int c,
                          __hip_bfloat16* __restrict__ hi, __hip_bfloat16* __restrict__ lo)
{
    int idx = blockIdx.x * blockDim.x + threadIdx.x;
    if (idx >= M_ * 1024) return;
    int m = idx >> 10, dd = idx & 1023;
    int d = c * 1024 + dd;
    float v = (d < D_) ? X[(size_t)m * D_ + d] : 0.0f;
    bsplit_(v, hi[idx], lo[idx]);
}

__global__ void k_split_flat(const float* __restrict__ src, int n,
                             __hip_bfloat16* __restrict__ hi, __hip_bfloat16* __restrict__ lo)
{
    int idx = blockIdx.x * blockDim.x + threadIdx.x;
    if (idx < n) bsplit_(src[idx], hi[idx], lo[idx]);
}

// Whh[j][e] f32 -> f16 pairs.  e2<64 -> Wrg[e2][768]; e2>=64 -> Wst[c][768][4]
__global__ void k_wgru_pack(const float* __restrict__ Whh,
                            unsigned int* __restrict__ Wrg, unsigned int* __restrict__ Wst)
{
    int idx = blockIdx.x * blockDim.x + threadIdx.x;
    if (idx >= 768 * 128) return;
    int j = idx / 128, e2 = idx % 128;
    union { unsigned int u; h2_t h; } c;
    c.h[0] = (_Float16)Whh[(size_t)j * 256 + 2 * e2];
    c.h[1] = (_Float16)Whh[(size_t)j * 256 + 2 * e2 + 1];
    if (e2 < 64) {
        Wrg[(size_t)e2 * 768 + j] = c.u;
    } else {
        int ee = e2 - 64, ch = ee >> 2, i = ee & 3;
        Wst[((size_t)ch * 768 + j) * 4 + i] = c.u;
    }
}

__global__ void k_prof(const float* __restrict__ profiles, const float* __restrict__ emP_w,
                       const float* __restrict__ emP_b, float* __restrict__ prof)
{
    int b = blockIdx.x, j = threadIdx.x;
    float acc = emP_b[j];
    for (int k = 0; k < PS_; ++k) acc += profiles[(size_t)b * PS_ + k] * emP_w[(size_t)k * PE_ + j];
    prof[(size_t)b * PE_ + j] = acc;
}

__global__ void k_fill_tp(const float* __restrict__ prof,
                          __hip_bfloat16* __restrict__ At_hi, __hip_bfloat16* __restrict__ At_lo)
{
    int idx = blockIdx.x * blockDim.x + threadIdx.x;
    if (idx >= M_ * PE_) return;
    int m = idx >> 6, pe = idx & 63;
    float v = prof[(size_t)(m & (B_ - 1)) * PE_ + pe];
    size_t o = (size_t)m * 320 + 256 + pe;
    bsplit_(v, At_hi[o], At_lo[o]);
}

// ---------------------------------------------------------------------------
// GRAM group attention
// ---------------------------------------------------------------------------
__global__ void k_group_embed(const float* __restrict__ PP, const float* __restrict__ Wa_b,
                              const float* __restrict__ Ua_w, const float* __restrict__ ini_embd,
                              const int* __restrict__ leaves1, const int* __restrict__ anc1,
                              const int* __restrict__ leaves2, const int* __restrict__ anc2,
                              float* __restrict__ embedG)
{
    int n = blockIdx.x;
    int lane = threadIdx.x;
    const int* lv; const int* ac; int L;
    if (n < G1N_) { L = G1L_; lv = leaves1 + (size_t)n * G1L_; ac = anc1 + (size_t)n * G1L_; }
    else { int n2 = n - G1N_; L = G2L_; lv = leaves2 + (size_t)n2 * G2L_; ac = anc2 + (size_t)n2 * G2L_; }

    float score[6]; int ai[6];
    for (int l = 0; l < L; ++l) {
        int li = lv[l]; int av = ac[l]; ai[l] = av;
        float s = 0.0f;
        for (int a = lane; a < A_; a += 64) {
            float hv = tanhf(PP[(size_t)li * 256 + a] + PP[(size_t)av * 256 + 128 + a] + Wa_b[a]);
            s += hv * Ua_w[a];
        }
        for (int o = 32; o; o >>= 1) s += __shfl_xor(s, o);
        score[l] = s;
    }
    float mx = -1e30f;
    for (int l = 0; l < L; ++l) mx = fmaxf(mx, score[l]);
    float w[6], sum = 0.0f;
    for (int l = 0; l < L; ++l) { w[l] = __expf(score[l] - mx); sum += w[l]; }
    float inv = 1.0f / sum;
    for (int e = lane; e < E_; e += 64) {
        float acc = 0.0f;
        for (int l = 0; l < L; ++l) acc += w[l] * inv * ini_embd[(size_t)ai[l] * E_ + e];
        embedG[(size_t)n * E_ + e] = acc;
    }
}

// ---------------------------------------------------------------------------
// GRU scan v4: 128 wgs x 768 threads, 2 samples/wg.
// f16 weights: e<128 in registers (16 x uint4), e>=128 streamed (uint4, L2).
// h as packed f16x2 in LDS (h2S); true h lives in updater registers.
// Inner product via fdot2 (2 MAC/inst, f32 accumulate).
// ---------------------------------------------------------------------------
__global__ __launch_bounds__(768, 3)
void k_gru4(const float* __restrict__ gx, const unsigned int* __restrict__ Wrg,
            const uint4* __restrict__ Wst, const float* __restrict__ bhh,
            const int* __restrict__ X_len, float* __restrict__ gruo,
            __hip_bfloat16* __restrict__ At_hi, __hip_bfloat16* __restrict__ At_lo)
{
    const int wg = blockIdx.x;          // 0..127
    const int s0 = wg * 2;
    const int tid = threadIdx.x;        // 0..767 = output column j

    __shared__ uint4 h2S[2][32];        // [sample][chunk of 4 e2-pairs] = 1 KB
    __shared__ float ghS[2][768];       // 6 KB
    __shared__ float gxnS[2][256];      // 2 KB

    if (tid < 256) ((unsigned int*)h2S)[tid] = 0u;

    // one-time: load register-resident weight half (e2 = 0..63)
    uint4 Wr[16];
#pragma unroll
    for (int c = 0; c < 16; ++c) {
        Wr[c].x = Wrg[(size_t)(4 * c + 0) * 768 + tid];
        Wr[c].y = Wrg[(size_t)(4 * c + 1) * 768 + tid];
        Wr[c].z = Wrg[(size_t)(4 * c + 2) * 768 + tid];
        Wr[c].w = Wrg[(size_t)(4 * c + 3) * 768 + tid];
    }

    float hreg = 0.0f;                  // updater threads (tid<512) own h[s][hj]
    int len = 0;
    if (tid < 512) len = X_len[s0 + (tid >> 8)];
    const float bj = bhh[tid];
    __syncthreads();

    for (int t = 0; t < T_; ++t) {
        const size_t gb = ((size_t)t * B_ + s0) * 768;
        float g0 = gx[gb + tid];
        float g1 = gx[gb + 768 + tid];

        float a0 = bj, a1 = bj;
#pragma unroll
        for (int c = 0; c < 32; ++c) {
            uint4 w = (c < 16) ? Wr[c] : Wst[(size_t)(c - 16) * 768 + tid];
            uint4 h0 = h2S[0][c];
            uint4 h1 = h2S[1][c];
            a0 = dot2_(w.x, h0.x, a0); a0 = dot2_(w.y, h0.y, a0);
            a0 = dot2_(w.z, h0.z, a0); a0 = dot2_(w.w, h0.w, a0);
            a1 = dot2_(w.x, h1.x, a1); a1 = dot2_(w.y, h1.y, a1);
            a1 = dot2_(w.z, h1.z, a1); a1 = dot2_(w.w, h1.w, a1);
        }

        if (tid < 512) {
            ghS[0][tid] = a0 + g0;
            ghS[1][tid] = a1 + g1;
        } else {
            ghS[0][tid] = a0; ghS[1][tid] = a1;
            gxnS[0][tid - 512] = g0; gxnS[1][tid - 512] = g1;
        }
        __syncthreads();

        if (tid < 512) {
            const int s = tid >> 8, hj = tid & 255;
            float r  = sigmoidf_(ghS[s][hj]);
            float z  = sigmoidf_(ghS[s][256 + hj]);
            float nn = tanhf(gxnS[s][hj] + r * ghS[s][512 + hj]);
            float hnew = (1.0f - z) * nn + z * hreg;
            bool msk = (t < len);
            hreg = msk ? hnew : hreg;
            float ov = msk ? hreg : 0.0f;
            size_t m = (size_t)t * B_ + (s0 + s);
            gruo[m * H_ + hj] = ov;
            size_t o = m * 320 + hj;
            bsplit_(ov, At_hi[o], At_lo[o]);
            // publish packed f16x2 h via lane pairing
            float partner = __shfl_xor(hreg, 1);
            if (!(hj & 1)) {
                union { unsigned int u; h2_t h; } p;
                p.h[0] = (_Float16)hreg;
                p.h[1] = (_Float16)partner;
                ((unsigned int*)&h2S[s][0])[hj >> 1] = p.u;
            }
        }
        __syncthreads();
    }
}

// ---------------------------------------------------------------------------
// Value-memory scan
// ---------------------------------------------------------------------------
__global__ __launch_bounds__(256)
void k_mem(const float* __restrict__ slotw, const float* __restrict__ era,
           const float* __restrict__ iniVam, float* __restrict__ readv)
{
    const int b = blockIdx.x;
    const int tid = threadIdx.x;
    const int v = tid & (V_ - 1);
    const int sh = tid >> 7;
    const int sbase = sh * 64;

    float VM[64];
#pragma unroll 8
    for (int i = 0; i < 64; ++i) VM[i] = iniVam[(size_t)(sbase + i) * V_ + v];

    __shared__ float swL[S_];
    __shared__ float eaL[2 * V_];
    __shared__ float part[V_];

    for (int t = 0; t < T_; ++t) {
        size_t m = (size_t)t * B_ + b;
        if (tid < S_) swL[tid] = slotw[m * S_ + tid];
        eaL[tid] = era[m * (2 * V_) + tid];
        __syncthreads();

        float er = eaL[v], ad = eaL[V_ + v];
        float acc = 0.0f;
#pragma unroll 8
        for (int i = 0; i < 64; ++i) {
            float sv = swL[sbase + i];
            float vm = VM[i];
            acc += sv * vm;
            VM[i] = vm * (1.0f - sv * er) + sv * ad;
        }
        if (sh == 1) part[v] = acc;
        __syncthreads();
        if (sh == 0) readv[m * V_ + v] = acc + part[v];
        __syncthreads();
    }
}

// ---------------------------------------------------------------------------
// F = [gruo | read | prof2] as f16 (single plane, feeds f16 out-GEMM)
// ---------------------------------------------------------------------------
__global__ __launch_bounds__(256)
void k_build_final(const float* __restrict__ gruo, const float* __restrict__ readv,
                   const float* __restrict__ prof, const float* __restrict__ attnP_w,
                   const float* __restrict__ attnP_b, _Float16* __restrict__ F)
{
    const int m = blockIdx.x;
    const int b = m & (B_ - 1);
    const int tid = threadIdx.x;
    __shared__ float rd[V_];
    __shared__ float pf[PE_];
    if (tid < V_) rd[tid] = readv[(size_t)m * V_ + tid];
    if (tid < PE_) pf[tid] = prof[(size_t)b * PE_ + tid];
    __syncthreads();

    size_t base = (size_t)m * KF_;
    F[base + tid] = (_Float16)gruo[(size_t)m * H_ + tid];
    if (tid < V_) F[base + H_ + tid] = (_Float16)rd[tid];
    if (tid < PE_) {
        float a = attnP_b[tid];
        for (int k = 0; k < PE_; ++k) a += pf[k] * attnP_w[(size_t)k * PE_ + tid];
        for (int k = 0; k < V_; ++k) a += rd[k] * attnP_w[(size_t)(PE_ + k) * PE_ + tid];
        a = fmaxf(a, 0.0f);
        F[base + H_ + V_ + tid] = (_Float16)(pf[tid] * a);
    }
}

// ---------------------------------------------------------------------------
// Softmaxes
// ---------------------------------------------------------------------------
__global__ void k_softmax128(float* __restrict__ C)
{
    const int m = blockIdx.x;
    const size_t base = (size_t)m * S_;
    const int lane = threadIdx.x;
    float a = C[base + lane], b = C[base + 64 + lane];
    float mx = fmaxf(a, b);
    for (int o = 32; o; o >>= 1) mx = fmaxf(mx, __shfl_xor(mx, o));
    float e0 = __expf(a - mx), e1 = __expf(b - mx);
    float s = e0 + e1;
    for (int o = 32; o; o >>= 1) s += __shfl_xor(s, o);
    float inv = 1.0f / s;
    C[base + lane] = e0 * inv;
    C[base + 64 + lane] = e1 * inv;
}

__global__ __launch_bounds__(256)
void k_softmax2000(float* __restrict__ C)
{
    const int m = blockIdx.x;
    const size_t base = (size_t)m * D_;
    const int tid = threadIdx.x;
    const int wid = tid >> 6, lane = tid & 63;
    __shared__ float red[4], red2[4];

    float v[8];
#pragma unroll
    for (int i = 0; i < 8; ++i) {
        int d = i * 256 + tid;
        v[i] = (d < D_) ? C[base + d] : -1e30f;
    }
    float mx = v[0];
#pragma unroll
    for (int i = 1; i < 8; ++i) mx = fmaxf(mx, v[i]);
    for (int o = 32; o; o >>= 1) mx = fmaxf(mx, __shfl_xor(mx, o));
    if (lane == 0) red[wid] = mx;
    __syncthreads();
    mx = fmaxf(fmaxf(red[0], red[1]), fmaxf(red[2], red[3]));

    float sum = 0.0f;
#pragma unroll
    for (int i = 0; i < 8; ++i) { v[i] = __expf(v[i] - mx); sum += v[i]; }
    for (int o = 32; o; o >>= 1) sum += __shfl_xor(sum, o);
    if (lane == 0) red2[wid] = sum;
    __syncthreads();
    sum = red2[0] + red2[1] + red2[2] + red2[3];
    float inv = 1.0f / sum;
#pragma unroll
    for (int i = 0; i < 8; ++i) {
        int d = i * 256 + tid;
        if (d < D_) C[base + d] = v[i] * inv;
    }
}

// ---------------------------------------------------------------------------
// Launch
// ---------------------------------------------------------------------------
extern "C" void kernel_launch(void* const* d_in, const int* in_sizes, int n_in,
                              void* d_out, int out_size, void* d_ws, size_t ws_size,
                              hipStream_t stream)
{
    const float* X        = (const float*)d_in[0];
    const float* profiles = (const float*)d_in[1];
    const float* ini_embd = (const float*)d_in[2];
    const float* Wa_w     = (const float*)d_in[3];
    const float* Wa_b     = (const float*)d_in[4];
    const float* Ua_w     = (const float*)d_in[5];
    const float* gru_Wih  = (const float*)d_in[6];
    const float* gru_Whh  = (const float*)d_in[7];
    const float* gru_bih  = (const float*)d_in[8];
    const float* gru_bhh  = (const float*)d_in[9];
    const float* tranH_w  = (const float*)d_in[10];
    const float* tranH_b  = (const float*)d_in[11];
    const float* out_w    = (const float*)d_in[12];
    const float* out_b    = (const float*)d_in[13];
    const float* erase_w  = (const float*)d_in[14];
    const float* erase_b  = (const float*)d_in[15];
    const float* add_w    = (const float*)d_in[16];
    const float* add_b    = (const float*)d_in[17];
    const float* iniVam   = (const float*)d_in[18];
    const float* emP_w    = (const float*)d_in[19];
    const float* emP_b    = (const float*)d_in[20];
    const float* attnP_w  = (const float*)d_in[21];
    const float* attnP_b  = (const float*)d_in[22];
    const int* KMIds   = (const int*)d_in[23];
    const int* leaves1 = (const int*)d_in[24];
    const int* anc1    = (const int*)d_in[25];
    const int* leaves2 = (const int*)d_in[26];
    const int* anc2    = (const int*)d_in[27];
    const int* mapInfo = (const int*)d_in[28];
    const int* X_len   = (const int*)d_in[29];

    char* ws = (char*)d_ws;
    float* out = (float*)d_out;
    typedef __hip_bfloat16 bf16;

    // ---- workspace layout (bytes) ----
    const size_t R0 = 0;            // 67,108,864 multi-use region
    const size_t R1 = 67108864;     // 16,777,216 : Xe f32; later gruo f32
    const size_t R2 = 83886080;     // 16,777,216 : era f32
    const size_t R3 = 100663296;    // 20,971,520 : At_hi/At_lo; later slotw/readv
    size_t P = 121634816;
    const size_t E0HI = P; P += 524288;
    const size_t E0LO = P; P += 524288;
    const size_t E1HI = P; P += 524288;
    const size_t E1LO = P; P += 524288;
    const size_t OWF  = P; P += 1835008;  // out_w^T f16 [2048][448]
    const size_t WIHI = P; P += 393216;
    const size_t WILO = P; P += 393216;
    const size_t WEHI = P; P += 131072;
    const size_t WELO = P; P += 131072;
    const size_t THHI = P; P += 163840;
    const size_t THLO = P; P += 163840;
    const size_t KMHI = P; P += 65536;
    const size_t KMLO = P; P += 65536;
    const size_t WRG  = P; P += 196608;   // Whh f16 reg-half [64][768] uint
    const size_t WST  = P; P += 196608;   // Whh f16 stream-half [16][768][4] uint
    const size_t PROF = P; P += 65536;
    const size_t BEA  = P; P += 1024;
    const size_t W2O  = P; P += 262144;

    float* PP      = (float*)(ws + R0);
    float* embG    = (float*)(ws + R0 + 12288000);
    bf16*  Xc_hi   = (bf16*)(ws + R0);
    bf16*  Xc_lo   = (bf16*)(ws + R0 + 33554432);
    float* gx      = (float*)(ws + R0);
    bf16*  Xe_hi   = (bf16*)(ws + R0 + 50331648);
    bf16*  Xe_lo   = (bf16*)(ws + R0 + 58720256);
    bf16*  tran_hi = (bf16*)(ws + R0);
    bf16*  tran_lo = (bf16*)(ws + R0 + 8388608);
    _Float16* F16  = (_Float16*)(ws + R0);
    float* Xe_f    = (float*)(ws + R1);
    float* gruo    = (float*)(ws + R1);
    float* era     = (float*)(ws + R2);
    bf16*  At_hi   = (bf16*)(ws + R3);
    bf16*  At_lo   = (bf16*)(ws + R3 + 10485760);
    float* slotw   = (float*)(ws + R3);
    float* readv   = (float*)(ws + R3 + 10485760);
    bf16*  E0hi = (bf16*)(ws + E0HI); bf16* E0lo = (bf16*)(ws + E0LO);
    bf16*  E1hi = (bf16*)(ws + E1HI); bf16* E1lo = (bf16*)(ws + E1LO);
    _Float16* OWf = (_Float16*)(ws + OWF);
    bf16*  WIhi = (bf16*)(ws + WIHI); bf16* WIlo = (bf16*)(ws + WILO);
    bf16*  WEhi = (bf16*)(ws + WEHI); bf16* WElo = (bf16*)(ws + WELO);
    bf16*  THhi = (bf16*)(ws + THHI); bf16* THlo = (bf16*)(ws + THLO);
    bf16*  KMhi = (bf16*)(ws + KMHI); bf16* KMlo = (bf16*)(ws + KMLO);
    unsigned int* Wrg = (unsigned int*)(ws + WRG);
    unsigned int* Wst = (unsigned int*)(ws + WST);
    float* prof = (float*)(ws + PROF);
    float* bea  = (float*)(ws + BEA);
    float* W2p  = (float*)(ws + W2O);

    // ---- weight packs ----
    k_pack_w2<<<(E_ * 2 * A_ + 255) / 256, 256, 0, stream>>>(Wa_w, W2p);
    k_weaT_split<<<(256 * 256 + 255) / 256, 256, 0, stream>>>(erase_w, add_w, erase_b, add_b, WEhi, WElo, bea);
    k_wih_split<<<(768 * 256 + 255) / 256, 256, 0, stream>>>(gru_Wih, WIhi, WIlo);
    k_tranHT_split<<<(256 * 320 + 255) / 256, 256, 0, stream>>>(tranH_w, THhi, THlo);
    k_outWT_f16<<<(2048 * 448 + 255) / 256, 256, 0, stream>>>(out_w, OWf);
    k_km_split<<<(S_ * E_ + 255) / 256, 256, 0, stream>>>(ini_embd, KMIds, KMhi, KMlo);
    k_wgru_pack<<<(768 * 128 + 255) / 256, 256, 0, stream>>>(gru_Whh, Wrg, Wst);
    k_prof<<<B_, PE_, 0, stream>>>(profiles, emP_w, emP_b, prof);

    // ---- ontology attention -> embedMat ----
    {
        dim3 blk(16, 16);
        dim3 grid(4, (TN_ + 63) / 64);
        k_gemm<64, 64, 16, 4, 4><<<grid, blk, 0, stream>>>(ini_embd, W2p, PP, TN_, 256, E_);
    }
    k_group_embed<<<G1N_ + G2N_, 64, 0, stream>>>(PP, Wa_b, Ua_w, ini_embd,
                                                  leaves1, anc1, leaves2, anc2, embG);
    k_embMT_chunk<<<(256 * 1024) / 256, 256, 0, stream>>>(embG, mapInfo, 0, E0hi, E0lo);
    k_embMT_chunk<<<(256 * 1024) / 256, 256, 0, stream>>>(embG, mapInfo, 1, E1hi, E1lo);

    // ---- Xe = X @ embM (split bf16 3-phase, K-chunked, fp32 accumulate) ----
    k_x_chunk<<<(M_ * 1024) / 256, 256, 0, stream>>>(X, 0, Xc_hi, Xc_lo);
    k_mgemm3<0, false, 0, 3, 0><<<128 * 2, 256, 0, stream>>>(Xc_hi, Xc_lo, E0hi, E0lo,
        nullptr, Xe_f, nullptr, nullptr, 1024, 256, 2);
    k_x_chunk<<<(M_ * 1024) / 256, 256, 0, stream>>>(X, 1, Xc_hi, Xc_lo);
    k_mgemm3<0, true, 0, 3, 0><<<128 * 2, 256, 0, stream>>>(Xc_hi, Xc_lo, E1hi, E1lo,
        nullptr, Xe_f, nullptr, nullptr, 1024, 256, 2);

    k_split_flat<<<(M_ * 256) / 256, 256, 0, stream>>>(Xe_f, M_ * 256, Xe_hi, Xe_lo);

    // ---- era = gates(Xe @ Wea + bea) ----
    k_mgemm3<1, false, 0, 3, 0><<<128 * 2, 256, 0, stream>>>(Xe_hi, Xe_lo, WEhi, WElo,
        bea, era, nullptr, nullptr, 256, 256, 2);

    // ---- gx = Xe @ Wih^T + bih ----
    k_mgemm3<0, false, 0, 3, 0><<<128 * 6, 256, 0, stream>>>(Xe_hi, Xe_lo, WIhi, WIlo,
        gru_bih, gx, nullptr, nullptr, 256, 768, 6);

    // ---- GRU scan v4 ----
    k_gru4<<<128, 768, 0, stream>>>(gx, Wrg, (const uint4*)Wst, gru_bhh, X_len,
                                    gruo, At_hi, At_lo);
    k_fill_tp<<<(M_ * PE_) / 256, 256, 0, stream>>>(prof, At_hi, At_lo);

    // ---- tran = [gruo|prof] @ tranH + b ----
    k_mgemm3<0, false, 1, 3, 0><<<128 * 2, 256, 0, stream>>>(At_hi, At_lo, THhi, THlo,
        tranH_b, nullptr, tran_hi, tran_lo, 320, 256, 2);

    // ---- slot logits = tran @ KM^T ----
    k_mgemm3<0, false, 0, 3, 0><<<128 * 1, 256, 0, stream>>>(tran_hi, tran_lo, KMhi, KMlo,
        nullptr, slotw, nullptr, nullptr, 256, 128, 1);

    k_softmax128<<<M_, 64, 0, stream>>>(slotw);
    k_mem<<<B_, 256, 0, stream>>>(slotw, era, iniVam, readv);
    k_build_final<<<M_, 256, 0, stream>>>(gruo, readv, prof, attnP_w, attnP_b, F16);

    // ---- logits = F @ out_w + out_b (f16 1-phase MFMA) ----
    k_mgemm3<0, false, 0, 1, 1><<<128 * 16, 256, 0, stream>>>(
        (const bf16*)F16, nullptr, (const bf16*)OWf, nullptr,
        out_b, out, nullptr, nullptr, 448, 2000, 16);

    k_softmax2000<<<M_, 256, 0, stream>>>(out);
}

// Round 7
// 886.717 us; speedup vs baseline: 3.4930x; 1.2341x over previous
//
#include <hip/hip_runtime.h>
#include <hip/hip_bf16.h>
#include <cmath>

#define T_  64
#define B_  256
#define D_  2000
#define TN_ 3000
#define E_  256
#define H_  256
#define A_  128
#define V_  128
#define PS_ 64
#define PE_ 64
#define S_  128
#define G1N_ 1500
#define G1L_ 4
#define G2N_ 1500
#define G2L_ 6
#define M_  (T_ * B_)
#define KF_ (H_ + V_ + PE_)

typedef __attribute__((ext_vector_type(8))) short short8_t;
typedef __attribute__((ext_vector_type(4))) float floatx4;
typedef _Float16 __attribute__((ext_vector_type(2))) h2_t;
typedef _Float16 __attribute__((ext_vector_type(8))) h8_t;

static __device__ __forceinline__ float sigmoidf_(float x) {
    return 1.0f / (1.0f + __expf(-x));
}

static __device__ __forceinline__ void bsplit_(float v, __hip_bfloat16& hi, __hip_bfloat16& lo) {
    hi = __float2bfloat16(v);
    lo = __float2bfloat16(v - __bfloat162float(hi));
}

static __device__ __forceinline__ float dot2_(unsigned int w, unsigned int h, float acc) {
    union { unsigned int u; h2_t h; } cw, ch;
    cw.u = w; ch.u = h;
#if __has_builtin(__builtin_amdgcn_fdot2)
    return __builtin_amdgcn_fdot2(cw.h, ch.h, acc, false);
#else
    return acc + (float)cw.h[0] * (float)ch.h[0] + (float)cw.h[1] * (float)ch.h[1];
#endif
}

template<int DT>
static __device__ __forceinline__ floatx4 mfma16_(short8_t a, short8_t b, floatx4 c) {
    if constexpr (DT == 0) {
        return __builtin_amdgcn_mfma_f32_16x16x32_bf16(a, b, c, 0, 0, 0);
    } else {
        union { short8_t s; h8_t h; } ua, ub;
        ua.s = a; ub.s = b;
        return __builtin_amdgcn_mfma_f32_16x16x32_f16(ua.h, ub.h, c, 0, 0, 0);
    }
}

// ---------------------------------------------------------------------------
// Split MFMA GEMM: C = A @ B. DT=0: bf16 planes (NPH=3 -> fp32-grade).
// DT=1: f16 planes, NPH=1 (f16 hi-only, ~2^-12 accurate).
// B given as BT[Npad][K] row-major. M mult 128, K mult 32, Npad = nblk*128.
// ---------------------------------------------------------------------------
template<int EPI, bool ACCUM, int OUTMODE, int NPH, int DT>
__global__ __launch_bounds__(256)
void k_mgemm3(const __hip_bfloat16* __restrict__ Ahi, const __hip_bfloat16* __restrict__ Alo,
              const __hip_bfloat16* __restrict__ Bhi, const __hip_bfloat16* __restrict__ Blo,
              const float* __restrict__ bias, float* __restrict__ Cf,
              __hip_bfloat16* __restrict__ Chi, __hip_bfloat16* __restrict__ Clo,
              int K, int Nreal, int nblk)
{
    __shared__ __align__(16) short As[4096];
    __shared__ __align__(16) short Bs[4096];

    const int tid  = threadIdx.x;
    const int lane = tid & 63;
    const int w    = tid >> 6;
    const int wm   = w >> 1, wn = w & 1;
    const int lr   = lane & 15;
    const int lkc  = lane >> 4;

    const int bx = blockIdx.x;
    const int m0 = (bx / nblk) * 128;
    const int n0 = (bx % nblk) * 128;

    const int fa = 2 * w;
    const size_t aoff0 = (size_t)(m0 + fa * 16 + lr) * K + lkc * 8;
    const size_t aoff1 = aoff0 + (size_t)16 * K;
    const size_t boff0 = (size_t)(n0 + fa * 16 + lr) * K + lkc * 8;
    const size_t boff1 = boff0 + (size_t)16 * K;

    floatx4 acc[4][4];
#pragma unroll
    for (int i = 0; i < 4; ++i)
#pragma unroll
        for (int j = 0; j < 4; ++j) acc[i][j] = floatx4{0.f, 0.f, 0.f, 0.f};

#pragma unroll 1
    for (int ph = 0; ph < NPH; ++ph) {
        const __hip_bfloat16* Ap = (ph == 2) ? Alo : Ahi;
        const __hip_bfloat16* Bp = (ph == 1) ? Blo : Bhi;

        short8_t ra0 = *(const short8_t*)(const void*)(Ap + aoff0);
        short8_t ra1 = *(const short8_t*)(const void*)(Ap + aoff1);
        short8_t rb0 = *(const short8_t*)(const void*)(Bp + boff0);
        short8_t rb1 = *(const short8_t*)(const void*)(Bp + boff1);

        for (int k0 = 0; k0 < K; k0 += 32) {
            __syncthreads();
            *(short8_t*)(void*)&As[(fa    ) * 512 + lane * 8] = ra0;
            *(short8_t*)(void*)&As[(fa + 1) * 512 + lane * 8] = ra1;
            *(short8_t*)(void*)&Bs[(fa    ) * 512 + lane * 8] = rb0;
            *(short8_t*)(void*)&Bs[(fa + 1) * 512 + lane * 8] = rb1;
            __syncthreads();

            if (k0 + 32 < K) {
                int kn = k0 + 32;
                ra0 = *(const short8_t*)(const void*)(Ap + aoff0 + kn);
                ra1 = *(const short8_t*)(const void*)(Ap + aoff1 + kn);
                rb0 = *(const short8_t*)(const void*)(Bp + boff0 + kn);
                rb1 = *(const short8_t*)(const void*)(Bp + boff1 + kn);
            }

            short8_t af[4], bf[4];
#pragma unroll
            for (int i = 0; i < 4; ++i)
                af[i] = *(const short8_t*)(const void*)&As[(wm * 4 + i) * 512 + lane * 8];
#pragma unroll
            for (int j = 0; j < 4; ++j)
                bf[j] = *(const short8_t*)(const void*)&Bs[(wn * 4 + j) * 512 + lane * 8];
#pragma unroll
            for (int i = 0; i < 4; ++i)
#pragma unroll
                for (int j = 0; j < 4; ++j)
                    acc[i][j] = mfma16_<DT>(af[i], bf[j], acc[i][j]);
        }
    }

    // C/D layout (m89-verified): col=lane&15, row=(lane>>4)*4+r
#pragma unroll
    for (int i = 0; i < 4; ++i) {
        const int row = m0 + wm * 64 + i * 16 + (lane >> 4) * 4;
#pragma unroll
        for (int j = 0; j < 4; ++j) {
            const int col = n0 + wn * 64 + j * 16 + (lane & 15);
            if (col < Nreal) {
                float bv = bias ? bias[col] : 0.0f;
#pragma unroll
                for (int r = 0; r < 4; ++r) {
                    float v = acc[i][j][r] + bv;
                    if (EPI == 1) v = (col < 128) ? sigmoidf_(v) : tanhf(v);
                    size_t o = (size_t)(row + r) * Nreal + col;
                    if (OUTMODE == 0) {
                        if (ACCUM) v += Cf[o];
                        Cf[o] = v;
                    } else {
                        __hip_bfloat16 h, l;
                        bsplit_(v, h, l);
                        Chi[o] = h; Clo[o] = l;
                    }
                }
            }
        }
    }
}

// ---------------------------------------------------------------------------
// fp32 tiled GEMM (PP = ini_embd @ W2 only)
// ---------------------------------------------------------------------------
template<int BM, int BN, int BK, int TM, int TN>
__global__ __launch_bounds__(256)
void k_gemm(const float* __restrict__ A, const float* __restrict__ B,
            float* __restrict__ C, int M, int N, int K)
{
    __shared__ float As[BK][BM + 4];
    __shared__ float Bs[BK][BN + 4];
    const int tid = threadIdx.y * blockDim.x + threadIdx.x;
    const int m0 = blockIdx.y * BM;
    const int n0 = blockIdx.x * BN;
    float acc[TM][TN];
#pragma unroll
    for (int i = 0; i < TM; ++i)
#pragma unroll
        for (int j = 0; j < TN; ++j) acc[i][j] = 0.0f;
    for (int k0 = 0; k0 < K; k0 += BK) {
#pragma unroll
        for (int i = tid; i < BM * BK; i += 256) {
            int r = i / BK, c = i % BK;
            int m = m0 + r;
            As[c][r] = (m < M) ? A[(size_t)m * K + k0 + c] : 0.0f;
        }
#pragma unroll
        for (int i = tid; i < BK * BN; i += 256) {
            int r = i / BN, c = i % BN;
            Bs[r][c] = B[(size_t)(k0 + r) * N + n0 + c];
        }
        __syncthreads();
#pragma unroll
        for (int kk = 0; kk < BK; ++kk) {
            float a[TM], b[TN];
#pragma unroll
            for (int i = 0; i < TM; ++i) a[i] = As[kk][threadIdx.y * TM + i];
#pragma unroll
            for (int j = 0; j < TN; ++j) b[j] = Bs[kk][threadIdx.x * TN + j];
#pragma unroll
            for (int i = 0; i < TM; ++i)
#pragma unroll
                for (int j = 0; j < TN; ++j) acc[i][j] += a[i] * b[j];
        }
        __syncthreads();
    }
#pragma unroll
    for (int i = 0; i < TM; ++i) {
        int m = m0 + threadIdx.y * TM + i;
        if (m >= M) continue;
#pragma unroll
        for (int j = 0; j < TN; ++j)
            C[(size_t)m * N + n0 + threadIdx.x * TN + j] = acc[i][j];
    }
}

// ---------------------------------------------------------------------------
// Pack / convert / split kernels
// ---------------------------------------------------------------------------
__global__ void k_pack_w2(const float* __restrict__ Wa_w, float* __restrict__ W2)
{
    int idx = blockIdx.x * blockDim.x + threadIdx.x;
    if (idx >= E_ * 2 * A_) return;
    int e = idx / (2 * A_), j = idx % (2 * A_);
    W2[idx] = (j < A_) ? Wa_w[(size_t)e * A_ + j]
                       : Wa_w[(size_t)(E_ + e) * A_ + (j - A_)];
}

__global__ void k_weaT_split(const float* __restrict__ erase_w, const float* __restrict__ add_w,
                             const float* __restrict__ erase_b, const float* __restrict__ add_b,
                             __hip_bfloat16* __restrict__ Whi, __hip_bfloat16* __restrict__ Wlo,
                             float* __restrict__ bea)
{
    int idx = blockIdx.x * blockDim.x + threadIdx.x;
    if (idx < 256 * 256) {
        int n = idx / 256, k = idx % 256;
        float v = (n < V_) ? erase_w[(size_t)k * V_ + n] : add_w[(size_t)k * V_ + (n - V_)];
        bsplit_(v, Whi[idx], Wlo[idx]);
    }
    if (idx < 2 * V_) bea[idx] = (idx < V_) ? erase_b[idx] : add_b[idx - V_];
}

__global__ void k_wih_split(const float* __restrict__ Wih,
                            __hip_bfloat16* __restrict__ hi, __hip_bfloat16* __restrict__ lo)
{
    int idx = blockIdx.x * blockDim.x + threadIdx.x;
    if (idx < 768 * 256) bsplit_(Wih[idx], hi[idx], lo[idx]);
}

__global__ void k_tranHT_split(const float* __restrict__ tranH_w,
                               __hip_bfloat16* __restrict__ hi, __hip_bfloat16* __restrict__ lo)
{
    int idx = blockIdx.x * blockDim.x + threadIdx.x;
    if (idx >= 256 * 320) return;
    int n = idx / 320, k = idx % 320;
    bsplit_(tranH_w[(size_t)k * 256 + n], hi[idx], lo[idx]);
}

// out_w transposed -> single f16 plane
__global__ void k_outWT_f16(const float* __restrict__ out_w, _Float16* __restrict__ dst)
{
    int idx = blockIdx.x * blockDim.x + threadIdx.x;
    if (idx >= 2048 * 448) return;
    int n = idx / 448, k = idx % 448;
    float v = (n < D_) ? out_w[(size_t)k * D_ + n] : 0.0f;
    dst[idx] = (_Float16)v;
}

__global__ void k_km_split(const float* __restrict__ ini_embd, const int* __restrict__ KMIds,
                           __hip_bfloat16* __restrict__ hi, __hip_bfloat16* __restrict__ lo)
{
    int idx = blockIdx.x * blockDim.x + threadIdx.x;
    if (idx >= S_ * E_) return;
    int s = idx / E_, k = idx % E_;
    bsplit_(ini_embd[(size_t)KMIds[s] * E_ + k], hi[idx], lo[idx]);
}

__global__ void k_embMT_chunk(const float* __restrict__ embG, const int* __restrict__ mapInfo,
                              int c, __hip_bfloat16* __restrict__ hi, __hip_bfloat16* __restrict__ lo)
{
    int idx = blockIdx.x * blockDim.x + threadIdx.x;
    if (idx >= 256 * 1024) return;
    int e = idx >> 10, dd = idx & 1023;
    int d = c * 1024 + dd;
    float v = (d < D_) ? embG[(size_t)mapInfo[d] * E_ + e] : 0.0f;
    bsplit_(v, hi[idx], lo[idx]);
}

__global__ void k_x_chunk(const float* __restrict__ X, int c,
                          __hip_bfloat16* __restrict__ hi, __hip_bfloat16* __restrict__ lo)
{
    int idx = blockIdx.x * blockDim.x + threadIdx.x;
    if (idx >= M_ * 1024) return;
    int m = idx >> 10, dd = idx & 1023;
    int d = c * 1024 + dd;
    float v = (d < D_) ? X[(size_t)m * D_ + d] : 0.0f;
    bsplit_(v, hi[idx], lo[idx]);
}

__global__ void k_split_flat(const float* __restrict__ src, int n,
                             __hip_bfloat16* __restrict__ hi, __hip_bfloat16* __restrict__ lo)
{
    int idx = blockIdx.x * blockDim.x + threadIdx.x;
    if (idx < n) bsplit_(src[idx], hi[idx], lo[idx]);
}

// Whh[j][e] f32 -> f16 pairs.  e2<64 -> Wrg[e2][768]; e2>=64 -> Wst[c][768][4]
__global__ void k_wgru_pack(const float* __restrict__ Whh,
                            unsigned int* __restrict__ Wrg, unsigned int* __restrict__ Wst)
{
    int idx = blockIdx.x * blockDim.x + threadIdx.x;
    if (idx >= 768 * 128) return;
    int j = idx / 128, e2 = idx % 128;
    union { unsigned int u; h2_t h; } c;
    c.h[0] = (_Float16)Whh[(size_t)j * 256 + 2 * e2];
    c.h[1] = (_Float16)Whh[(size_t)j * 256 + 2 * e2 + 1];
    if (e2 < 64) {
        Wrg[(size_t)e2 * 768 + j] = c.u;
    } else {
        int ee = e2 - 64, ch = ee >> 2, i = ee & 3;
        Wst[((size_t)ch * 768 + j) * 4 + i] = c.u;
    }
}

__global__ void k_prof(const float* __restrict__ profiles, const float* __restrict__ emP_w,
                       const float* __restrict__ emP_b, float* __restrict__ prof)
{
    int b = blockIdx.x, j = threadIdx.x;
    float acc = emP_b[j];
    for (int k = 0; k < PS_; ++k) acc += profiles[(size_t)b * PS_ + k] * emP_w[(size_t)k * PE_ + j];
    prof[(size_t)b * PE_ + j] = acc;
}

__global__ void k_fill_tp(const float* __restrict__ prof,
                          __hip_bfloat16* __restrict__ At_hi, __hip_bfloat16* __restrict__ At_lo)
{
    int idx = blockIdx.x * blockDim.x + threadIdx.x;
    if (idx >= M_ * PE_) return;
    int m = idx >> 6, pe = idx & 63;
    float v = prof[(size_t)(m & (B_ - 1)) * PE_ + pe];
    size_t o = (size_t)m * 320 + 256 + pe;
    bsplit_(v, At_hi[o], At_lo[o]);
}

// ---------------------------------------------------------------------------
// GRAM group attention
// ---------------------------------------------------------------------------
__global__ void k_group_embed(const float* __restrict__ PP, const float* __restrict__ Wa_b,
                              const float* __restrict__ Ua_w, const float* __restrict__ ini_embd,
                              const int* __restrict__ leaves1, const int* __restrict__ anc1,
                              const int* __restrict__ leaves2, const int* __restrict__ anc2,
                              float* __restrict__ embedG)
{
    int n = blockIdx.x;
    int lane = threadIdx.x;
    const int* lv; const int* ac; int L;
    if (n < G1N_) { L = G1L_; lv = leaves1 + (size_t)n * G1L_; ac = anc1 + (size_t)n * G1L_; }
    else { int n2 = n - G1N_; L = G2L_; lv = leaves2 + (size_t)n2 * G2L_; ac = anc2 + (size_t)n2 * G2L_; }

    float score[6]; int ai[6];
    for (int l = 0; l < L; ++l) {
        int li = lv[l]; int av = ac[l]; ai[l] = av;
        float s = 0.0f;
        for (int a = lane; a < A_; a += 64) {
            float hv = tanhf(PP[(size_t)li * 256 + a] + PP[(size_t)av * 256 + 128 + a] + Wa_b[a]);
            s += hv * Ua_w[a];
        }
        for (int o = 32; o; o >>= 1) s += __shfl_xor(s, o);
        score[l] = s;
    }
    float mx = -1e30f;
    for (int l = 0; l < L; ++l) mx = fmaxf(mx, score[l]);
    float w[6], sum = 0.0f;
    for (int l = 0; l < L; ++l) { w[l] = __expf(score[l] - mx); sum += w[l]; }
    float inv = 1.0f / sum;
    for (int e = lane; e < E_; e += 64) {
        float acc = 0.0f;
        for (int l = 0; l < L; ++l) acc += w[l] * inv * ini_embd[(size_t)ai[l] * E_ + e];
        embedG[(size_t)n * E_ + e] = acc;
    }
}

// ---------------------------------------------------------------------------
// GRU scan v4: 128 wgs x 768 threads, 2 samples/wg.
// f16 weights: e<128 in registers (16 x uint4), e>=128 streamed (uint4, L2).
// ---------------------------------------------------------------------------
__global__ __launch_bounds__(768, 3)
void k_gru4(const float* __restrict__ gx, const unsigned int* __restrict__ Wrg,
            const uint4* __restrict__ Wst, const float* __restrict__ bhh,
            const int* __restrict__ X_len, float* __restrict__ gruo,
            __hip_bfloat16* __restrict__ At_hi, __hip_bfloat16* __restrict__ At_lo)
{
    const int wg = blockIdx.x;          // 0..127
    const int s0 = wg * 2;
    const int tid = threadIdx.x;        // 0..767 = output column j

    __shared__ uint4 h2S[2][32];        // [sample][chunk of 4 e2-pairs] = 1 KB
    __shared__ float ghS[2][768];       // 6 KB
    __shared__ float gxnS[2][256];      // 2 KB

    if (tid < 256) ((unsigned int*)h2S)[tid] = 0u;

    // one-time: load register-resident weight half (e2 = 0..63)
    uint4 Wr[16];
#pragma unroll
    for (int c = 0; c < 16; ++c) {
        Wr[c].x = Wrg[(size_t)(4 * c + 0) * 768 + tid];
        Wr[c].y = Wrg[(size_t)(4 * c + 1) * 768 + tid];
        Wr[c].z = Wrg[(size_t)(4 * c + 2) * 768 + tid];
        Wr[c].w = Wrg[(size_t)(4 * c + 3) * 768 + tid];
    }

    float hreg = 0.0f;                  // updater threads (tid<512) own h[s][hj]
    int len = 0;
    if (tid < 512) len = X_len[s0 + (tid >> 8)];
    const float bj = bhh[tid];
    __syncthreads();

    for (int t = 0; t < T_; ++t) {
        const size_t gb = ((size_t)t * B_ + s0) * 768;
        float g0 = gx[gb + tid];
        float g1 = gx[gb + 768 + tid];

        float a0 = bj, a1 = bj;
#pragma unroll
        for (int c = 0; c < 32; ++c) {
            uint4 w = (c < 16) ? Wr[c] : Wst[(size_t)(c - 16) * 768 + tid];
            uint4 h0 = h2S[0][c];
            uint4 h1 = h2S[1][c];
            a0 = dot2_(w.x, h0.x, a0); a0 = dot2_(w.y, h0.y, a0);
            a0 = dot2_(w.z, h0.z, a0); a0 = dot2_(w.w, h0.w, a0);
            a1 = dot2_(w.x, h1.x, a1); a1 = dot2_(w.y, h1.y, a1);
            a1 = dot2_(w.z, h1.z, a1); a1 = dot2_(w.w, h1.w, a1);
        }

        if (tid < 512) {
            ghS[0][tid] = a0 + g0;
            ghS[1][tid] = a1 + g1;
        } else {
            ghS[0][tid] = a0; ghS[1][tid] = a1;
            gxnS[0][tid - 512] = g0; gxnS[1][tid - 512] = g1;
        }
        __syncthreads();

        if (tid < 512) {
            const int s = tid >> 8, hj = tid & 255;
            float r  = sigmoidf_(ghS[s][hj]);
            float z  = sigmoidf_(ghS[s][256 + hj]);
            float nn = tanhf(gxnS[s][hj] + r * ghS[s][512 + hj]);
            float hnew = (1.0f - z) * nn + z * hreg;
            bool msk = (t < len);
            hreg = msk ? hnew : hreg;
            float ov = msk ? hreg : 0.0f;
            size_t m = (size_t)t * B_ + (s0 + s);
            gruo[m * H_ + hj] = ov;
            size_t o = m * 320 + hj;
            bsplit_(ov, At_hi[o], At_lo[o]);
            float partner = __shfl_xor(hreg, 1);
            if (!(hj & 1)) {
                union { unsigned int u; h2_t h; } p;
                p.h[0] = (_Float16)hreg;
                p.h[1] = (_Float16)partner;
                ((unsigned int*)&h2S[s][0])[hj >> 1] = p.u;
            }
        }
        __syncthreads();
    }
}

// ---------------------------------------------------------------------------
// Value-memory scan — VM fully register-resident (all indices compile-time).
// Thread owns v = tid&127, s-half = tid>>7 -> VM[64] in VGPRs.
// 4 partial accumulators break the read-dot dependency chain.
// ---------------------------------------------------------------------------
__global__ __launch_bounds__(256)
void k_mem(const float* __restrict__ slotw, const float* __restrict__ era,
           const float* __restrict__ iniVam, float* __restrict__ readv)
{
    const int b = blockIdx.x;
    const int tid = threadIdx.x;
    const int v = tid & (V_ - 1);
    const int sh = tid >> 7;
    const int sbase = sh * 64;

    float VM[64];
#pragma unroll
    for (int i = 0; i < 64; ++i) VM[i] = iniVam[(size_t)(sbase + i) * V_ + v];

    __shared__ float swL[S_];
    __shared__ float eaL[2 * V_];
    __shared__ float part[V_];

    for (int t = 0; t < T_; ++t) {
        size_t m = (size_t)t * B_ + b;
        if (tid < S_) swL[tid] = slotw[m * S_ + tid];
        eaL[tid] = era[m * (2 * V_) + tid];
        __syncthreads();

        float er = eaL[v], ad = eaL[V_ + v];
        float p0 = 0.0f, p1 = 0.0f, p2 = 0.0f, p3 = 0.0f;
#pragma unroll
        for (int i = 0; i < 16; ++i) {
            float s0 = swL[sbase + 4 * i];
            float s1 = swL[sbase + 4 * i + 1];
            float s2 = swL[sbase + 4 * i + 2];
            float s3 = swL[sbase + 4 * i + 3];
            float v0 = VM[4 * i], v1 = VM[4 * i + 1], v2 = VM[4 * i + 2], v3 = VM[4 * i + 3];
            p0 += s0 * v0; p1 += s1 * v1; p2 += s2 * v2; p3 += s3 * v3;
            VM[4 * i]     = v0 * (1.0f - s0 * er) + s0 * ad;
            VM[4 * i + 1] = v1 * (1.0f - s1 * er) + s1 * ad;
            VM[4 * i + 2] = v2 * (1.0f - s2 * er) + s2 * ad;
            VM[4 * i + 3] = v3 * (1.0f - s3 * er) + s3 * ad;
        }
        float acc = (p0 + p1) + (p2 + p3);
        if (sh == 1) part[v] = acc;
        __syncthreads();
        if (sh == 0) readv[m * V_ + v] = acc + part[v];
        __syncthreads();
    }
}

// ---------------------------------------------------------------------------
// F = [gruo | read | prof2] as f16 (single plane, feeds f16 out-GEMM)
// ---------------------------------------------------------------------------
__global__ __launch_bounds__(256)
void k_build_final(const float* __restrict__ gruo, const float* __restrict__ readv,
                   const float* __restrict__ prof, const float* __restrict__ attnP_w,
                   const float* __restrict__ attnP_b, _Float16* __restrict__ F)
{
    const int m = blockIdx.x;
    const int b = m & (B_ - 1);
    const int tid = threadIdx.x;
    __shared__ float rd[V_];
    __shared__ float pf[PE_];
    if (tid < V_) rd[tid] = readv[(size_t)m * V_ + tid];
    if (tid < PE_) pf[tid] = prof[(size_t)b * PE_ + tid];
    __syncthreads();

    size_t base = (size_t)m * KF_;
    F[base + tid] = (_Float16)gruo[(size_t)m * H_ + tid];
    if (tid < V_) F[base + H_ + tid] = (_Float16)rd[tid];
    if (tid < PE_) {
        float a = attnP_b[tid];
        for (int k = 0; k < PE_; ++k) a += pf[k] * attnP_w[(size_t)k * PE_ + tid];
        for (int k = 0; k < V_; ++k) a += rd[k] * attnP_w[(size_t)(PE_ + k) * PE_ + tid];
        a = fmaxf(a, 0.0f);
        F[base + H_ + V_ + tid] = (_Float16)(pf[tid] * a);
    }
}

// ---------------------------------------------------------------------------
// Softmaxes
// ---------------------------------------------------------------------------
__global__ void k_softmax128(float* __restrict__ C)
{
    const int m = blockIdx.x;
    const size_t base = (size_t)m * S_;
    const int lane = threadIdx.x;
    float a = C[base + lane], b = C[base + 64 + lane];
    float mx = fmaxf(a, b);
    for (int o = 32; o; o >>= 1) mx = fmaxf(mx, __shfl_xor(mx, o));
    float e0 = __expf(a - mx), e1 = __expf(b - mx);
    float s = e0 + e1;
    for (int o = 32; o; o >>= 1) s += __shfl_xor(s, o);
    float inv = 1.0f / s;
    C[base + lane] = e0 * inv;
    C[base + 64 + lane] = e1 * inv;
}

__global__ __launch_bounds__(256)
void k_softmax2000(float* __restrict__ C)
{
    const int m = blockIdx.x;
    const size_t base = (size_t)m * D_;
    const int tid = threadIdx.x;
    const int wid = tid >> 6, lane = tid & 63;
    __shared__ float red[4], red2[4];

    float v[8];
#pragma unroll
    for (int i = 0; i < 8; ++i) {
        int d = i * 256 + tid;
        v[i] = (d < D_) ? C[base + d] : -1e30f;
    }
    float mx = v[0];
#pragma unroll
    for (int i = 1; i < 8; ++i) mx = fmaxf(mx, v[i]);
    for (int o = 32; o; o >>= 1) mx = fmaxf(mx, __shfl_xor(mx, o));
    if (lane == 0) red[wid] = mx;
    __syncthreads();
    mx = fmaxf(fmaxf(red[0], red[1]), fmaxf(red[2], red[3]));

    float sum = 0.0f;
#pragma unroll
    for (int i = 0; i < 8; ++i) { v[i] = __expf(v[i] - mx); sum += v[i]; }
    for (int o = 32; o; o >>= 1) sum += __shfl_xor(sum, o);
    if (lane == 0) red2[wid] = sum;
    __syncthreads();
    sum = red2[0] + red2[1] + red2[2] + red2[3];
    float inv = 1.0f / sum;
#pragma unroll
    for (int i = 0; i < 8; ++i) {
        int d = i * 256 + tid;
        if (d < D_) C[base + d] = v[i] * inv;
    }
}

// ---------------------------------------------------------------------------
// Launch
// ---------------------------------------------------------------------------
extern "C" void kernel_launch(void* const* d_in, const int* in_sizes, int n_in,
                              void* d_out, int out_size, void* d_ws, size_t ws_size,
                              hipStream_t stream)
{
    const float* X        = (const float*)d_in[0];
    const float* profiles = (const float*)d_in[1];
    const float* ini_embd = (const float*)d_in[2];
    const float* Wa_w     = (const float*)d_in[3];
    const float* Wa_b     = (const float*)d_in[4];
    const float* Ua_w     = (const float*)d_in[5];
    const float* gru_Wih  = (const float*)d_in[6];
    const float* gru_Whh  = (const float*)d_in[7];
    const float* gru_bih  = (const float*)d_in[8];
    const float* gru_bhh  = (const float*)d_in[9];
    const float* tranH_w  = (const float*)d_in[10];
    const float* tranH_b  = (const float*)d_in[11];
    const float* out_w    = (const float*)d_in[12];
    const float* out_b    = (const float*)d_in[13];
    const float* erase_w  = (const float*)d_in[14];
    const float* erase_b  = (const float*)d_in[15];
    const float* add_w    = (const float*)d_in[16];
    const float* add_b    = (const float*)d_in[17];
    const float* iniVam   = (const float*)d_in[18];
    const float* emP_w    = (const float*)d_in[19];
    const float* emP_b    = (const float*)d_in[20];
    const float* attnP_w  = (const float*)d_in[21];
    const float* attnP_b  = (const float*)d_in[22];
    const int* KMIds   = (const int*)d_in[23];
    const int* leaves1 = (const int*)d_in[24];
    const int* anc1    = (const int*)d_in[25];
    const int* leaves2 = (const int*)d_in[26];
    const int* anc2    = (const int*)d_in[27];
    const int* mapInfo = (const int*)d_in[28];
    const int* X_len   = (const int*)d_in[29];

    char* ws = (char*)d_ws;
    float* out = (float*)d_out;
    typedef __hip_bfloat16 bf16;

    // ---- workspace layout (bytes) ----
    const size_t R0 = 0;            // 67,108,864 multi-use region
    const size_t R1 = 67108864;     // 16,777,216 : Xe f32; later gruo f32
    const size_t R2 = 83886080;     // 16,777,216 : era f32
    const size_t R3 = 100663296;    // 20,971,520 : At_hi/At_lo; later slotw/readv
    size_t P = 121634816;
    const size_t E0HI = P; P += 524288;
    const size_t E0LO = P; P += 524288;
    const size_t E1HI = P; P += 524288;
    const size_t E1LO = P; P += 524288;
    const size_t OWF  = P; P += 1835008;  // out_w^T f16 [2048][448]
    const size_t WIHI = P; P += 393216;
    const size_t WILO = P; P += 393216;
    const size_t WEHI = P; P += 131072;
    const size_t WELO = P; P += 131072;
    const size_t THHI = P; P += 163840;
    const size_t THLO = P; P += 163840;
    const size_t KMHI = P; P += 65536;
    const size_t KMLO = P; P += 65536;
    const size_t WRG  = P; P += 196608;   // Whh f16 reg-half [64][768] uint
    const size_t WST  = P; P += 196608;   // Whh f16 stream-half [16][768][4] uint
    const size_t PROF = P; P += 65536;
    const size_t BEA  = P; P += 1024;
    const size_t W2O  = P; P += 262144;

    float* PP      = (float*)(ws + R0);
    float* embG    = (float*)(ws + R0 + 12288000);
    bf16*  Xc_hi   = (bf16*)(ws + R0);
    bf16*  Xc_lo   = (bf16*)(ws + R0 + 33554432);
    float* gx      = (float*)(ws + R0);
    bf16*  Xe_hi   = (bf16*)(ws + R0 + 50331648);
    bf16*  Xe_lo   = (bf16*)(ws + R0 + 58720256);
    bf16*  tran_hi = (bf16*)(ws + R0);
    bf16*  tran_lo = (bf16*)(ws + R0 + 8388608);
    _Float16* F16  = (_Float16*)(ws + R0);
    float* Xe_f    = (float*)(ws + R1);
    float* gruo    = (float*)(ws + R1);
    float* era     = (float*)(ws + R2);
    bf16*  At_hi   = (bf16*)(ws + R3);
    bf16*  At_lo   = (bf16*)(ws + R3 + 10485760);
    float* slotw   = (float*)(ws + R3);
    float* readv   = (float*)(ws + R3 + 10485760);
    bf16*  E0hi = (bf16*)(ws + E0HI); bf16* E0lo = (bf16*)(ws + E0LO);
    bf16*  E1hi = (bf16*)(ws + E1HI); bf16* E1lo = (bf16*)(ws + E1LO);
    _Float16* OWf = (_Float16*)(ws + OWF);
    bf16*  WIhi = (bf16*)(ws + WIHI); bf16* WIlo = (bf16*)(ws + WILO);
    bf16*  WEhi = (bf16*)(ws + WEHI); bf16* WElo = (bf16*)(ws + WELO);
    bf16*  THhi = (bf16*)(ws + THHI); bf16* THlo = (bf16*)(ws + THLO);
    bf16*  KMhi = (bf16*)(ws + KMHI); bf16* KMlo = (bf16*)(ws + KMLO);
    unsigned int* Wrg = (unsigned int*)(ws + WRG);
    unsigned int* Wst = (unsigned int*)(ws + WST);
    float* prof = (float*)(ws + PROF);
    float* bea  = (float*)(ws + BEA);
    float* W2p  = (float*)(ws + W2O);

    // ---- weight packs ----
    k_pack_w2<<<(E_ * 2 * A_ + 255) / 256, 256, 0, stream>>>(Wa_w, W2p);
    k_weaT_split<<<(256 * 256 + 255) / 256, 256, 0, stream>>>(erase_w, add_w, erase_b, add_b, WEhi, WElo, bea);
    k_wih_split<<<(768 * 256 + 255) / 256, 256, 0, stream>>>(gru_Wih, WIhi, WIlo);
    k_tranHT_split<<<(256 * 320 + 255) / 256, 256, 0, stream>>>(tranH_w, THhi, THlo);
    k_outWT_f16<<<(2048 * 448 + 255) / 256, 256, 0, stream>>>(out_w, OWf);
    k_km_split<<<(S_ * E_ + 255) / 256, 256, 0, stream>>>(ini_embd, KMIds, KMhi, KMlo);
    k_wgru_pack<<<(768 * 128 + 255) / 256, 256, 0, stream>>>(gru_Whh, Wrg, Wst);
    k_prof<<<B_, PE_, 0, stream>>>(profiles, emP_w, emP_b, prof);

    // ---- ontology attention -> embedMat ----
    {
        dim3 blk(16, 16);
        dim3 grid(4, (TN_ + 63) / 64);
        k_gemm<64, 64, 16, 4, 4><<<grid, blk, 0, stream>>>(ini_embd, W2p, PP, TN_, 256, E_);
    }
    k_group_embed<<<G1N_ + G2N_, 64, 0, stream>>>(PP, Wa_b, Ua_w, ini_embd,
                                                  leaves1, anc1, leaves2, anc2, embG);
    k_embMT_chunk<<<(256 * 1024) / 256, 256, 0, stream>>>(embG, mapInfo, 0, E0hi, E0lo);
    k_embMT_chunk<<<(256 * 1024) / 256, 256, 0, stream>>>(embG, mapInfo, 1, E1hi, E1lo);

    // ---- Xe = X @ embM (split bf16 3-phase, K-chunked, fp32 accumulate) ----
    k_x_chunk<<<(M_ * 1024) / 256, 256, 0, stream>>>(X, 0, Xc_hi, Xc_lo);
    k_mgemm3<0, false, 0, 3, 0><<<128 * 2, 256, 0, stream>>>(Xc_hi, Xc_lo, E0hi, E0lo,
        nullptr, Xe_f, nullptr, nullptr, 1024, 256, 2);
    k_x_chunk<<<(M_ * 1024) / 256, 256, 0, stream>>>(X, 1, Xc_hi, Xc_lo);
    k_mgemm3<0, true, 0, 3, 0><<<128 * 2, 256, 0, stream>>>(Xc_hi, Xc_lo, E1hi, E1lo,
        nullptr, Xe_f, nullptr, nullptr, 1024, 256, 2);

    k_split_flat<<<(M_ * 256) / 256, 256, 0, stream>>>(Xe_f, M_ * 256, Xe_hi, Xe_lo);

    // ---- era = gates(Xe @ Wea + bea) ----
    k_mgemm3<1, false, 0, 3, 0><<<128 * 2, 256, 0, stream>>>(Xe_hi, Xe_lo, WEhi, WElo,
        bea, era, nullptr, nullptr, 256, 256, 2);

    // ---- gx = Xe @ Wih^T + bih ----
    k_mgemm3<0, false, 0, 3, 0><<<128 * 6, 256, 0, stream>>>(Xe_hi, Xe_lo, WIhi, WIlo,
        gru_bih, gx, nullptr, nullptr, 256, 768, 6);

    // ---- GRU scan v4 ----
    k_gru4<<<128, 768, 0, stream>>>(gx, Wrg, (const uint4*)Wst, gru_bhh, X_len,
                                    gruo, At_hi, At_lo);
    k_fill_tp<<<(M_ * PE_) / 256, 256, 0, stream>>>(prof, At_hi, At_lo);

    // ---- tran = [gruo|prof] @ tranH + b ----
    k_mgemm3<0, false, 1, 3, 0><<<128 * 2, 256, 0, stream>>>(At_hi, At_lo, THhi, THlo,
        tranH_b, nullptr, tran_hi, tran_lo, 320, 256, 2);

    // ---- slot logits = tran @ KM^T ----
    k_mgemm3<0, false, 0, 3, 0><<<128 * 1, 256, 0, stream>>>(tran_hi, tran_lo, KMhi, KMlo,
        nullptr, slotw, nullptr, nullptr, 256, 128, 1);

    k_softmax128<<<M_, 64, 0, stream>>>(slotw);
    k_mem<<<B_, 256, 0, stream>>>(slotw, era, iniVam, readv);
    k_build_final<<<M_, 256, 0, stream>>>(gruo, readv, prof, attnP_w, attnP_b, F16);

    // ---- logits = F @ out_w + out_b (f16 1-phase MFMA) ----
    k_mgemm3<0, false, 0, 1, 1><<<128 * 16, 256, 0, stream>>>(
        (const bf16*)F16, nullptr, (const bf16*)OWf, nullptr,
        out_b, out, nullptr, nullptr, 448, 2000, 16);

    k_softmax2000<<<M_, 256, 0, stream>>>(out);
}

// Round 8
// 648.018 us; speedup vs baseline: 4.7797x; 1.3684x over previous
//
#include <hip/hip_runtime.h>
#include <hip/hip_bf16.h>
#include <cmath>

#define T_  64
#define B_  256
#define D_  2000
#define TN_ 3000
#define E_  256
#define H_  256
#define A_  128
#define V_  128
#define PS_ 64
#define PE_ 64
#define S_  128
#define G1N_ 1500
#define G1L_ 4
#define G2N_ 1500
#define G2L_ 6
#define M_  (T_ * B_)
#define KF_ (H_ + V_ + PE_)
#define NREG 28   // Whh f16 chunks held in registers (of 32)

typedef __attribute__((ext_vector_type(8))) short short8_t;
typedef __attribute__((ext_vector_type(4))) float floatx4;
typedef _Float16 __attribute__((ext_vector_type(2))) h2_t;
typedef _Float16 __attribute__((ext_vector_type(8))) h8_t;

static __device__ __forceinline__ float sigmoidf_(float x) {
    return 1.0f / (1.0f + __expf(-x));
}

static __device__ __forceinline__ void bsplit_(float v, __hip_bfloat16& hi, __hip_bfloat16& lo) {
    hi = __float2bfloat16(v);
    lo = __float2bfloat16(v - __bfloat162float(hi));
}

static __device__ __forceinline__ float dot2_(unsigned int w, unsigned int h, float acc) {
    union { unsigned int u; h2_t h; } cw, ch;
    cw.u = w; ch.u = h;
#if __has_builtin(__builtin_amdgcn_fdot2)
    return __builtin_amdgcn_fdot2(cw.h, ch.h, acc, false);
#else
    return acc + (float)cw.h[0] * (float)ch.h[0] + (float)cw.h[1] * (float)ch.h[1];
#endif
}

template<int DT>
static __device__ __forceinline__ floatx4 mfma16_(short8_t a, short8_t b, floatx4 c) {
    if constexpr (DT == 0) {
        return __builtin_amdgcn_mfma_f32_16x16x32_bf16(a, b, c, 0, 0, 0);
    } else {
        union { short8_t s; h8_t h; } ua, ub;
        ua.s = a; ub.s = b;
        return __builtin_amdgcn_mfma_f32_16x16x32_f16(ua.h, ub.h, c, 0, 0, 0);
    }
}

// ---------------------------------------------------------------------------
// Split MFMA GEMM: C = A @ B. DT=0: bf16 planes (NPH=3 -> fp32-grade).
// DT=1: f16 planes, NPH=1 (f16 hi-only, ~2^-12 accurate).
// B given as BT[Npad][K] row-major. M mult 128, K mult 32, Npad = nblk*128.
// ---------------------------------------------------------------------------
template<int EPI, bool ACCUM, int OUTMODE, int NPH, int DT>
__global__ __launch_bounds__(256)
void k_mgemm3(const __hip_bfloat16* __restrict__ Ahi, const __hip_bfloat16* __restrict__ Alo,
              const __hip_bfloat16* __restrict__ Bhi, const __hip_bfloat16* __restrict__ Blo,
              const float* __restrict__ bias, float* __restrict__ Cf,
              __hip_bfloat16* __restrict__ Chi, __hip_bfloat16* __restrict__ Clo,
              int K, int Nreal, int nblk)
{
    __shared__ __align__(16) short As[4096];
    __shared__ __align__(16) short Bs[4096];

    const int tid  = threadIdx.x;
    const int lane = tid & 63;
    const int w    = tid >> 6;
    const int wm   = w >> 1, wn = w & 1;
    const int lr   = lane & 15;
    const int lkc  = lane >> 4;

    const int bx = blockIdx.x;
    const int m0 = (bx / nblk) * 128;
    const int n0 = (bx % nblk) * 128;

    const int fa = 2 * w;
    const size_t aoff0 = (size_t)(m0 + fa * 16 + lr) * K + lkc * 8;
    const size_t aoff1 = aoff0 + (size_t)16 * K;
    const size_t boff0 = (size_t)(n0 + fa * 16 + lr) * K + lkc * 8;
    const size_t boff1 = boff0 + (size_t)16 * K;

    floatx4 acc[4][4];
#pragma unroll
    for (int i = 0; i < 4; ++i)
#pragma unroll
        for (int j = 0; j < 4; ++j) acc[i][j] = floatx4{0.f, 0.f, 0.f, 0.f};

#pragma unroll 1
    for (int ph = 0; ph < NPH; ++ph) {
        const __hip_bfloat16* Ap = (ph == 2) ? Alo : Ahi;
        const __hip_bfloat16* Bp = (ph == 1) ? Blo : Bhi;

        short8_t ra0 = *(const short8_t*)(const void*)(Ap + aoff0);
        short8_t ra1 = *(const short8_t*)(const void*)(Ap + aoff1);
        short8_t rb0 = *(const short8_t*)(const void*)(Bp + boff0);
        short8_t rb1 = *(const short8_t*)(const void*)(Bp + boff1);

        for (int k0 = 0; k0 < K; k0 += 32) {
            __syncthreads();
            *(short8_t*)(void*)&As[(fa    ) * 512 + lane * 8] = ra0;
            *(short8_t*)(void*)&As[(fa + 1) * 512 + lane * 8] = ra1;
            *(short8_t*)(void*)&Bs[(fa    ) * 512 + lane * 8] = rb0;
            *(short8_t*)(void*)&Bs[(fa + 1) * 512 + lane * 8] = rb1;
            __syncthreads();

            if (k0 + 32 < K) {
                int kn = k0 + 32;
                ra0 = *(const short8_t*)(const void*)(Ap + aoff0 + kn);
                ra1 = *(const short8_t*)(const void*)(Ap + aoff1 + kn);
                rb0 = *(const short8_t*)(const void*)(Bp + boff0 + kn);
                rb1 = *(const short8_t*)(const void*)(Bp + boff1 + kn);
            }

            short8_t af[4], bf[4];
#pragma unroll
            for (int i = 0; i < 4; ++i)
                af[i] = *(const short8_t*)(const void*)&As[(wm * 4 + i) * 512 + lane * 8];
#pragma unroll
            for (int j = 0; j < 4; ++j)
                bf[j] = *(const short8_t*)(const void*)&Bs[(wn * 4 + j) * 512 + lane * 8];
#pragma unroll
            for (int i = 0; i < 4; ++i)
#pragma unroll
                for (int j = 0; j < 4; ++j)
                    acc[i][j] = mfma16_<DT>(af[i], bf[j], acc[i][j]);
        }
    }

    // C/D layout (m89-verified): col=lane&15, row=(lane>>4)*4+r
#pragma unroll
    for (int i = 0; i < 4; ++i) {
        const int row = m0 + wm * 64 + i * 16 + (lane >> 4) * 4;
#pragma unroll
        for (int j = 0; j < 4; ++j) {
            const int col = n0 + wn * 64 + j * 16 + (lane & 15);
            if (col < Nreal) {
                float bv = bias ? bias[col] : 0.0f;
#pragma unroll
                for (int r = 0; r < 4; ++r) {
                    float v = acc[i][j][r] + bv;
                    if (EPI == 1) v = (col < 128) ? sigmoidf_(v) : tanhf(v);
                    size_t o = (size_t)(row + r) * Nreal + col;
                    if (OUTMODE == 0) {
                        if (ACCUM) v += Cf[o];
                        Cf[o] = v;
                    } else {
                        __hip_bfloat16 h, l;
                        bsplit_(v, h, l);
                        Chi[o] = h; Clo[o] = l;
                    }
                }
            }
        }
    }
}

// ---------------------------------------------------------------------------
// Fused Xe GEMM: Xe = X @ embM with A = f32 X [16384][2000] read directly,
// per-k-tile on-the-fly split into bf16 hi/lo LDS planes; 3 MFMA phases per
// tile (hi*hi + hi*lo + lo*hi); writes Xe hi/lo bf16 planes directly.
// B = embMT planes [256][2048] (pad cols zeroed). grid = 128*2.
// ---------------------------------------------------------------------------
__global__ __launch_bounds__(256)
void k_mgemmX(const float* __restrict__ A,
              const __hip_bfloat16* __restrict__ Bhi, const __hip_bfloat16* __restrict__ Blo,
              __hip_bfloat16* __restrict__ Chi, __hip_bfloat16* __restrict__ Clo)
{
    const int KP = 2048, KR = 2000, NN = 256, nblk = 2;
    __shared__ __align__(16) short Ah[4096];
    __shared__ __align__(16) short Al[4096];
    __shared__ __align__(16) short Bh[4096];
    __shared__ __align__(16) short Bl[4096];

    const int tid  = threadIdx.x;
    const int lane = tid & 63;
    const int w    = tid >> 6;
    const int wm   = w >> 1, wn = w & 1;
    const int lr   = lane & 15;
    const int lkc  = lane >> 4;

    const int bx = blockIdx.x;
    const int m0 = (bx / nblk) * 128;
    const int n0 = (bx % nblk) * 128;

    const int fa = 2 * w;
    const float* arow0 = A + (size_t)(m0 + fa * 16 + lr) * KR;
    const float* arow1 = arow0 + (size_t)16 * KR;
    const size_t boff0 = (size_t)(n0 + fa * 16 + lr) * KP + lkc * 8;
    const size_t boff1 = boff0 + (size_t)16 * KP;

    floatx4 acc[4][4];
#pragma unroll
    for (int i = 0; i < 4; ++i)
#pragma unroll
        for (int j = 0; j < 4; ++j) acc[i][j] = floatx4{0.f, 0.f, 0.f, 0.f};

    float a0v[8], a1v[8];
    short8_t bh0, bh1, bl0, bl1;

#define LOADA8(ROW, KB, DST)                                                  \
    if ((KB) + 7 < KR) {                                                      \
        float4 p_ = *(const float4*)((ROW) + (KB));                           \
        float4 q_ = *(const float4*)((ROW) + (KB) + 4);                       \
        DST[0]=p_.x; DST[1]=p_.y; DST[2]=p_.z; DST[3]=p_.w;                   \
        DST[4]=q_.x; DST[5]=q_.y; DST[6]=q_.z; DST[7]=q_.w;                   \
    } else {                                                                  \
        _Pragma("unroll")                                                     \
        for (int ii = 0; ii < 8; ++ii)                                        \
            DST[ii] = ((KB) + ii < KR) ? (ROW)[(KB) + ii] : 0.0f;             \
    }

    {
        const int kb = lkc * 8;
        LOADA8(arow0, kb, a0v)
        LOADA8(arow1, kb, a1v)
        bh0 = *(const short8_t*)(const void*)(Bhi + boff0);
        bh1 = *(const short8_t*)(const void*)(Bhi + boff1);
        bl0 = *(const short8_t*)(const void*)(Blo + boff0);
        bl1 = *(const short8_t*)(const void*)(Blo + boff1);
    }

    for (int k0 = 0; k0 < KP; k0 += 32) {
        __syncthreads();
        {
            short h8a[8], l8a[8], h8b[8], l8b[8];
#pragma unroll
            for (int i = 0; i < 8; ++i) {
                __hip_bfloat16 h, l;
                bsplit_(a0v[i], h, l);
                h8a[i] = *(short*)&h; l8a[i] = *(short*)&l;
                bsplit_(a1v[i], h, l);
                h8b[i] = *(short*)&h; l8b[i] = *(short*)&l;
            }
            *(short8_t*)(void*)&Ah[(fa    ) * 512 + lane * 8] = *(short8_t*)h8a;
            *(short8_t*)(void*)&Al[(fa    ) * 512 + lane * 8] = *(short8_t*)l8a;
            *(short8_t*)(void*)&Ah[(fa + 1) * 512 + lane * 8] = *(short8_t*)h8b;
            *(short8_t*)(void*)&Al[(fa + 1) * 512 + lane * 8] = *(short8_t*)l8b;
            *(short8_t*)(void*)&Bh[(fa    ) * 512 + lane * 8] = bh0;
            *(short8_t*)(void*)&Bh[(fa + 1) * 512 + lane * 8] = bh1;
            *(short8_t*)(void*)&Bl[(fa    ) * 512 + lane * 8] = bl0;
            *(short8_t*)(void*)&Bl[(fa + 1) * 512 + lane * 8] = bl1;
        }
        __syncthreads();

        if (k0 + 32 < KP) {
            const int kb = k0 + 32 + lkc * 8;
            LOADA8(arow0, kb, a0v)
            LOADA8(arow1, kb, a1v)
            bh0 = *(const short8_t*)(const void*)(Bhi + boff0 + k0 + 32);
            bh1 = *(const short8_t*)(const void*)(Bhi + boff1 + k0 + 32);
            bl0 = *(const short8_t*)(const void*)(Blo + boff0 + k0 + 32);
            bl1 = *(const short8_t*)(const void*)(Blo + boff1 + k0 + 32);
        }

        short8_t afh[4], afl[4], bfh[4], bfl[4];
#pragma unroll
        for (int i = 0; i < 4; ++i) {
            afh[i] = *(const short8_t*)(const void*)&Ah[(wm * 4 + i) * 512 + lane * 8];
            bfh[i] = *(const short8_t*)(const void*)&Bh[(wn * 4 + i) * 512 + lane * 8];
        }
#pragma unroll
        for (int i = 0; i < 4; ++i)
#pragma unroll
            for (int j = 0; j < 4; ++j)
                acc[i][j] = mfma16_<0>(afh[i], bfh[j], acc[i][j]);
#pragma unroll
        for (int j = 0; j < 4; ++j)
            bfl[j] = *(const short8_t*)(const void*)&Bl[(wn * 4 + j) * 512 + lane * 8];
#pragma unroll
        for (int i = 0; i < 4; ++i)
#pragma unroll
            for (int j = 0; j < 4; ++j)
                acc[i][j] = mfma16_<0>(afh[i], bfl[j], acc[i][j]);
#pragma unroll
        for (int i = 0; i < 4; ++i)
            afl[i] = *(const short8_t*)(const void*)&Al[(wm * 4 + i) * 512 + lane * 8];
#pragma unroll
        for (int i = 0; i < 4; ++i)
#pragma unroll
            for (int j = 0; j < 4; ++j)
                acc[i][j] = mfma16_<0>(afl[i], bfh[j], acc[i][j]);
    }
#undef LOADA8

#pragma unroll
    for (int i = 0; i < 4; ++i) {
        const int row = m0 + wm * 64 + i * 16 + (lane >> 4) * 4;
#pragma unroll
        for (int j = 0; j < 4; ++j) {
            const int col = n0 + wn * 64 + j * 16 + (lane & 15);
#pragma unroll
            for (int r = 0; r < 4; ++r) {
                float v = acc[i][j][r];
                size_t o = (size_t)(row + r) * NN + col;
                __hip_bfloat16 h, l;
                bsplit_(v, h, l);
                Chi[o] = h; Clo[o] = l;
            }
        }
    }
}

// ---------------------------------------------------------------------------
// fp32 tiled GEMM (PP = ini_embd @ W2 only)
// ---------------------------------------------------------------------------
template<int BM, int BN, int BK, int TM, int TN>
__global__ __launch_bounds__(256)
void k_gemm(const float* __restrict__ A, const float* __restrict__ B,
            float* __restrict__ C, int M, int N, int K)
{
    __shared__ float As[BK][BM + 4];
    __shared__ float Bs[BK][BN + 4];
    const int tid = threadIdx.y * blockDim.x + threadIdx.x;
    const int m0 = blockIdx.y * BM;
    const int n0 = blockIdx.x * BN;
    float acc[TM][TN];
#pragma unroll
    for (int i = 0; i < TM; ++i)
#pragma unroll
        for (int j = 0; j < TN; ++j) acc[i][j] = 0.0f;
    for (int k0 = 0; k0 < K; k0 += BK) {
#pragma unroll
        for (int i = tid; i < BM * BK; i += 256) {
            int r = i / BK, c = i % BK;
            int m = m0 + r;
            As[c][r] = (m < M) ? A[(size_t)m * K + k0 + c] : 0.0f;
        }
#pragma unroll
        for (int i = tid; i < BK * BN; i += 256) {
            int r = i / BN, c = i % BN;
            Bs[r][c] = B[(size_t)(k0 + r) * N + n0 + c];
        }
        __syncthreads();
#pragma unroll
        for (int kk = 0; kk < BK; ++kk) {
            float a[TM], b[TN];
#pragma unroll
            for (int i = 0; i < TM; ++i) a[i] = As[kk][threadIdx.y * TM + i];
#pragma unroll
            for (int j = 0; j < TN; ++j) b[j] = Bs[kk][threadIdx.x * TN + j];
#pragma unroll
            for (int i = 0; i < TM; ++i)
#pragma unroll
                for (int j = 0; j < TN; ++j) acc[i][j] += a[i] * b[j];
        }
        __syncthreads();
    }
#pragma unroll
    for (int i = 0; i < TM; ++i) {
        int m = m0 + threadIdx.y * TM + i;
        if (m >= M) continue;
#pragma unroll
        for (int j = 0; j < TN; ++j)
            C[(size_t)m * N + n0 + threadIdx.x * TN + j] = acc[i][j];
    }
}

// ---------------------------------------------------------------------------
// Pack / convert / split kernels
// ---------------------------------------------------------------------------
__global__ void k_pack_w2(const float* __restrict__ Wa_w, float* __restrict__ W2)
{
    int idx = blockIdx.x * blockDim.x + threadIdx.x;
    if (idx >= E_ * 2 * A_) return;
    int e = idx / (2 * A_), j = idx % (2 * A_);
    W2[idx] = (j < A_) ? Wa_w[(size_t)e * A_ + j]
                       : Wa_w[(size_t)(E_ + e) * A_ + (j - A_)];
}

__global__ void k_weaT_split(const float* __restrict__ erase_w, const float* __restrict__ add_w,
                             const float* __restrict__ erase_b, const float* __restrict__ add_b,
                             __hip_bfloat16* __restrict__ Whi, __hip_bfloat16* __restrict__ Wlo,
                             float* __restrict__ bea)
{
    int idx = blockIdx.x * blockDim.x + threadIdx.x;
    if (idx < 256 * 256) {
        int n = idx / 256, k = idx % 256;
        float v = (n < V_) ? erase_w[(size_t)k * V_ + n] : add_w[(size_t)k * V_ + (n - V_)];
        bsplit_(v, Whi[idx], Wlo[idx]);
    }
    if (idx < 2 * V_) bea[idx] = (idx < V_) ? erase_b[idx] : add_b[idx - V_];
}

__global__ void k_wih_split(const float* __restrict__ Wih,
                            __hip_bfloat16* __restrict__ hi, __hip_bfloat16* __restrict__ lo)
{
    int idx = blockIdx.x * blockDim.x + threadIdx.x;
    if (idx < 768 * 256) bsplit_(Wih[idx], hi[idx], lo[idx]);
}

__global__ void k_tranHT_split(const float* __restrict__ tranH_w,
                               __hip_bfloat16* __restrict__ hi, __hip_bfloat16* __restrict__ lo)
{
    int idx = blockIdx.x * blockDim.x + threadIdx.x;
    if (idx >= 256 * 320) return;
    int n = idx / 320, k = idx % 320;
    bsplit_(tranH_w[(size_t)k * 256 + n], hi[idx], lo[idx]);
}

// out_w transposed -> single f16 plane
__global__ void k_outWT_f16(const float* __restrict__ out_w, _Float16* __restrict__ dst)
{
    int idx = blockIdx.x * blockDim.x + threadIdx.x;
    if (idx >= 2048 * 448) return;
    int n = idx / 448, k = idx % 448;
    float v = (n < D_) ? out_w[(size_t)k * D_ + n] : 0.0f;
    dst[idx] = (_Float16)v;
}

__global__ void k_km_split(const float* __restrict__ ini_embd, const int* __restrict__ KMIds,
                           __hip_bfloat16* __restrict__ hi, __hip_bfloat16* __restrict__ lo)
{
    int idx = blockIdx.x * blockDim.x + threadIdx.x;
    if (idx >= S_ * E_) return;
    int s = idx / E_, k = idx % E_;
    bsplit_(ini_embd[(size_t)KMIds[s] * E_ + k], hi[idx], lo[idx]);
}

// embMT full: dst[e][d] = bf16 split of embG[mapInfo[d]][e], d<2000 else 0
__global__ void k_embMT(const float* __restrict__ embG, const int* __restrict__ mapInfo,
                        __hip_bfloat16* __restrict__ hi, __hip_bfloat16* __restrict__ lo)
{
    int idx = blockIdx.x * blockDim.x + threadIdx.x;
    if (idx >= 256 * 2048) return;
    int e = idx >> 11, d = idx & 2047;
    float v = (d < D_) ? embG[(size_t)mapInfo[d] * E_ + e] : 0.0f;
    bsplit_(v, hi[idx], lo[idx]);
}

// Whh[j][e] f32 -> f16 pairs. e2 < 4*NREG -> Wrg[e2][768]; else Wst chunks
__global__ void k_wgru_pack(const float* __restrict__ Whh,
                            unsigned int* __restrict__ Wrg, unsigned int* __restrict__ Wst)
{
    int idx = blockIdx.x * blockDim.x + threadIdx.x;
    if (idx >= 768 * 128) return;
    int j = idx / 128, e2 = idx % 128;
    union { unsigned int u; h2_t h; } c;
    c.h[0] = (_Float16)Whh[(size_t)j * 256 + 2 * e2];
    c.h[1] = (_Float16)Whh[(size_t)j * 256 + 2 * e2 + 1];
    if (e2 < 4 * NREG) {
        Wrg[(size_t)e2 * 768 + j] = c.u;
    } else {
        int ee = e2 - 4 * NREG;
        Wst[((size_t)(ee >> 2) * 768 + j) * 4 + (ee & 3)] = c.u;
    }
}

__global__ void k_prof(const float* __restrict__ profiles, const float* __restrict__ emP_w,
                       const float* __restrict__ emP_b, float* __restrict__ prof)
{
    int b = blockIdx.x, j = threadIdx.x;
    float acc = emP_b[j];
    for (int k = 0; k < PS_; ++k) acc += profiles[(size_t)b * PS_ + k] * emP_w[(size_t)k * PE_ + j];
    prof[(size_t)b * PE_ + j] = acc;
}

__global__ void k_fill_tp(const float* __restrict__ prof,
                          __hip_bfloat16* __restrict__ At_hi, __hip_bfloat16* __restrict__ At_lo)
{
    int idx = blockIdx.x * blockDim.x + threadIdx.x;
    if (idx >= M_ * PE_) return;
    int m = idx >> 6, pe = idx & 63;
    float v = prof[(size_t)(m & (B_ - 1)) * PE_ + pe];
    size_t o = (size_t)m * 320 + 256 + pe;
    bsplit_(v, At_hi[o], At_lo[o]);
}

// ---------------------------------------------------------------------------
// GRAM group attention
// ---------------------------------------------------------------------------
__global__ void k_group_embed(const float* __restrict__ PP, const float* __restrict__ Wa_b,
                              const float* __restrict__ Ua_w, const float* __restrict__ ini_embd,
                              const int* __restrict__ leaves1, const int* __restrict__ anc1,
                              const int* __restrict__ leaves2, const int* __restrict__ anc2,
                              float* __restrict__ embedG)
{
    int n = blockIdx.x;
    int lane = threadIdx.x;
    const int* lv; const int* ac; int L;
    if (n < G1N_) { L = G1L_; lv = leaves1 + (size_t)n * G1L_; ac = anc1 + (size_t)n * G1L_; }
    else { int n2 = n - G1N_; L = G2L_; lv = leaves2 + (size_t)n2 * G2L_; ac = anc2 + (size_t)n2 * G2L_; }

    float score[6]; int ai[6];
    for (int l = 0; l < L; ++l) {
        int li = lv[l]; int av = ac[l]; ai[l] = av;
        float s = 0.0f;
        for (int a = lane; a < A_; a += 64) {
            float hv = tanhf(PP[(size_t)li * 256 + a] + PP[(size_t)av * 256 + 128 + a] + Wa_b[a]);
            s += hv * Ua_w[a];
        }
        for (int o = 32; o; o >>= 1) s += __shfl_xor(s, o);
        score[l] = s;
    }
    float mx = -1e30f;
    for (int l = 0; l < L; ++l) mx = fmaxf(mx, score[l]);
    float w[6], sum = 0.0f;
    for (int l = 0; l < L; ++l) { w[l] = __expf(score[l] - mx); sum += w[l]; }
    float inv = 1.0f / sum;
    for (int e = lane; e < E_; e += 64) {
        float acc = 0.0f;
        for (int l = 0; l < L; ++l) acc += w[l] * inv * ini_embd[(size_t)ai[l] * E_ + e];
        embedG[(size_t)n * E_ + e] = acc;
    }
}

// ---------------------------------------------------------------------------
// GRU scan v5: 256 wgs x 768 threads, 1 sample/wg (all CUs busy).
// f16 weights: NREG chunks in registers, rest streamed; h packed f16x2 in LDS.
// ---------------------------------------------------------------------------
__global__ __launch_bounds__(768, 3)
void k_gru5(const float* __restrict__ gx, const unsigned int* __restrict__ Wrg,
            const uint4* __restrict__ Wst, const float* __restrict__ bhh,
            const int* __restrict__ X_len, float* __restrict__ gruo,
            __hip_bfloat16* __restrict__ At_hi, __hip_bfloat16* __restrict__ At_lo)
{
    const int b = blockIdx.x;           // sample
    const int tid = threadIdx.x;        // gate-row j in [0,768)

    __shared__ uint4 h2S[32];           // packed f16x2 h (512 B)
    __shared__ float ghS[768];
    __shared__ float gxnS[256];

    if (tid < 128) ((unsigned int*)h2S)[tid] = 0u;

    uint4 Wr[NREG];
#pragma unroll
    for (int c = 0; c < NREG; ++c) {
        Wr[c].x = Wrg[(size_t)(4 * c + 0) * 768 + tid];
        Wr[c].y = Wrg[(size_t)(4 * c + 1) * 768 + tid];
        Wr[c].z = Wrg[(size_t)(4 * c + 2) * 768 + tid];
        Wr[c].w = Wrg[(size_t)(4 * c + 3) * 768 + tid];
    }

    float hreg = 0.0f;
    const int len = X_len[b];
    const float bj = bhh[tid];
    __syncthreads();

    for (int t = 0; t < T_; ++t) {
        float gxv = gx[((size_t)t * B_ + b) * 768 + tid];

        float a0 = bj;
#pragma unroll
        for (int c = 0; c < 32; ++c) {
            uint4 w = (c < NREG) ? Wr[c] : Wst[(size_t)(c - NREG) * 768 + tid];
            uint4 h = h2S[c];
            a0 = dot2_(w.x, h.x, a0);
            a0 = dot2_(w.y, h.y, a0);
            a0 = dot2_(w.z, h.z, a0);
            a0 = dot2_(w.w, h.w, a0);
        }

        if (tid < 512) ghS[tid] = a0 + gxv;
        else { ghS[tid] = a0; gxnS[tid - 512] = gxv; }
        __syncthreads();

        if (tid < 256) {
            float r  = sigmoidf_(ghS[tid]);
            float z  = sigmoidf_(ghS[256 + tid]);
            float nn = tanhf(gxnS[tid] + r * ghS[512 + tid]);
            float hnew = (1.0f - z) * nn + z * hreg;
            bool msk = (t < len);
            hreg = msk ? hnew : hreg;
            float ov = msk ? hreg : 0.0f;
            size_t m = (size_t)t * B_ + b;
            gruo[m * H_ + tid] = ov;
            size_t o = m * 320 + tid;
            bsplit_(ov, At_hi[o], At_lo[o]);
            float partner = __shfl_xor(hreg, 1);
            if (!(tid & 1)) {
                union { unsigned int u; h2_t h; } p;
                p.h[0] = (_Float16)hreg;
                p.h[1] = (_Float16)partner;
                ((unsigned int*)h2S)[tid >> 1] = p.u;
            }
        }
        __syncthreads();
    }
}

// ---------------------------------------------------------------------------
// Value-memory scan — VM fully register-resident
// ---------------------------------------------------------------------------
__global__ __launch_bounds__(256)
void k_mem(const float* __restrict__ slotw, const float* __restrict__ era,
           const float* __restrict__ iniVam, float* __restrict__ readv)
{
    const int b = blockIdx.x;
    const int tid = threadIdx.x;
    const int v = tid & (V_ - 1);
    const int sh = tid >> 7;
    const int sbase = sh * 64;

    float VM[64];
#pragma unroll
    for (int i = 0; i < 64; ++i) VM[i] = iniVam[(size_t)(sbase + i) * V_ + v];

    __shared__ float swL[S_];
    __shared__ float eaL[2 * V_];
    __shared__ float part[V_];

    for (int t = 0; t < T_; ++t) {
        size_t m = (size_t)t * B_ + b;
        if (tid < S_) swL[tid] = slotw[m * S_ + tid];
        eaL[tid] = era[m * (2 * V_) + tid];
        __syncthreads();

        float er = eaL[v], ad = eaL[V_ + v];
        float p0 = 0.0f, p1 = 0.0f, p2 = 0.0f, p3 = 0.0f;
#pragma unroll
        for (int i = 0; i < 16; ++i) {
            float s0 = swL[sbase + 4 * i];
            float s1 = swL[sbase + 4 * i + 1];
            float s2 = swL[sbase + 4 * i + 2];
            float s3 = swL[sbase + 4 * i + 3];
            float v0 = VM[4 * i], v1 = VM[4 * i + 1], v2 = VM[4 * i + 2], v3 = VM[4 * i + 3];
            p0 += s0 * v0; p1 += s1 * v1; p2 += s2 * v2; p3 += s3 * v3;
            VM[4 * i]     = v0 * (1.0f - s0 * er) + s0 * ad;
            VM[4 * i + 1] = v1 * (1.0f - s1 * er) + s1 * ad;
            VM[4 * i + 2] = v2 * (1.0f - s2 * er) + s2 * ad;
            VM[4 * i + 3] = v3 * (1.0f - s3 * er) + s3 * ad;
        }
        float acc = (p0 + p1) + (p2 + p3);
        if (sh == 1) part[v] = acc;
        __syncthreads();
        if (sh == 0) readv[m * V_ + v] = acc + part[v];
        __syncthreads();
    }
}

// ---------------------------------------------------------------------------
// F = [gruo | read | prof2] as f16 (feeds f16 out-GEMM)
// ---------------------------------------------------------------------------
__global__ __launch_bounds__(256)
void k_build_final(const float* __restrict__ gruo, const float* __restrict__ readv,
                   const float* __restrict__ prof, const float* __restrict__ attnP_w,
                   const float* __restrict__ attnP_b, _Float16* __restrict__ F)
{
    const int m = blockIdx.x;
    const int b = m & (B_ - 1);
    const int tid = threadIdx.x;
    __shared__ float rd[V_];
    __shared__ float pf[PE_];
    if (tid < V_) rd[tid] = readv[(size_t)m * V_ + tid];
    if (tid < PE_) pf[tid] = prof[(size_t)b * PE_ + tid];
    __syncthreads();

    size_t base = (size_t)m * KF_;
    F[base + tid] = (_Float16)gruo[(size_t)m * H_ + tid];
    if (tid < V_) F[base + H_ + tid] = (_Float16)rd[tid];
    if (tid < PE_) {
        float a = attnP_b[tid];
        for (int k = 0; k < PE_; ++k) a += pf[k] * attnP_w[(size_t)k * PE_ + tid];
        for (int k = 0; k < V_; ++k) a += rd[k] * attnP_w[(size_t)(PE_ + k) * PE_ + tid];
        a = fmaxf(a, 0.0f);
        F[base + H_ + V_ + tid] = (_Float16)(pf[tid] * a);
    }
}

// ---------------------------------------------------------------------------
// Softmaxes
// ---------------------------------------------------------------------------
__global__ void k_softmax128(float* __restrict__ C)
{
    const int m = blockIdx.x;
    const size_t base = (size_t)m * S_;
    const int lane = threadIdx.x;
    float a = C[base + lane], b = C[base + 64 + lane];
    float mx = fmaxf(a, b);
    for (int o = 32; o; o >>= 1) mx = fmaxf(mx, __shfl_xor(mx, o));
    float e0 = __expf(a - mx), e1 = __expf(b - mx);
    float s = e0 + e1;
    for (int o = 32; o; o >>= 1) s += __shfl_xor(s, o);
    float inv = 1.0f / s;
    C[base + lane] = e0 * inv;
    C[base + 64 + lane] = e1 * inv;
}

__global__ __launch_bounds__(256)
void k_softmax2000(float* __restrict__ C)
{
    const int m = blockIdx.x;
    const size_t base = (size_t)m * D_;
    const int tid = threadIdx.x;
    const int wid = tid >> 6, lane = tid & 63;
    __shared__ float red[4], red2[4];

    float v[8];
#pragma unroll
    for (int i = 0; i < 8; ++i) {
        int d = i * 256 + tid;
        v[i] = (d < D_) ? C[base + d] : -1e30f;
    }
    float mx = v[0];
#pragma unroll
    for (int i = 1; i < 8; ++i) mx = fmaxf(mx, v[i]);
    for (int o = 32; o; o >>= 1) mx = fmaxf(mx, __shfl_xor(mx, o));
    if (lane == 0) red[wid] = mx;
    __syncthreads();
    mx = fmaxf(fmaxf(red[0], red[1]), fmaxf(red[2], red[3]));

    float sum = 0.0f;
#pragma unroll
    for (int i = 0; i < 8; ++i) { v[i] = __expf(v[i] - mx); sum += v[i]; }
    for (int o = 32; o; o >>= 1) sum += __shfl_xor(sum, o);
    if (lane == 0) red2[wid] = sum;
    __syncthreads();
    sum = red2[0] + red2[1] + red2[2] + red2[3];
    float inv = 1.0f / sum;
#pragma unroll
    for (int i = 0; i < 8; ++i) {
        int d = i * 256 + tid;
        if (d < D_) C[base + d] = v[i] * inv;
    }
}

// ---------------------------------------------------------------------------
// Launch
// ---------------------------------------------------------------------------
extern "C" void kernel_launch(void* const* d_in, const int* in_sizes, int n_in,
                              void* d_out, int out_size, void* d_ws, size_t ws_size,
                              hipStream_t stream)
{
    const float* X        = (const float*)d_in[0];
    const float* profiles = (const float*)d_in[1];
    const float* ini_embd = (const float*)d_in[2];
    const float* Wa_w     = (const float*)d_in[3];
    const float* Wa_b     = (const float*)d_in[4];
    const float* Ua_w     = (const float*)d_in[5];
    const float* gru_Wih  = (const float*)d_in[6];
    const float* gru_Whh  = (const float*)d_in[7];
    const float* gru_bih  = (const float*)d_in[8];
    const float* gru_bhh  = (const float*)d_in[9];
    const float* tranH_w  = (const float*)d_in[10];
    const float* tranH_b  = (const float*)d_in[11];
    const float* out_w    = (const float*)d_in[12];
    const float* out_b    = (const float*)d_in[13];
    const float* erase_w  = (const float*)d_in[14];
    const float* erase_b  = (const float*)d_in[15];
    const float* add_w    = (const float*)d_in[16];
    const float* add_b    = (const float*)d_in[17];
    const float* iniVam   = (const float*)d_in[18];
    const float* emP_w    = (const float*)d_in[19];
    const float* emP_b    = (const float*)d_in[20];
    const float* attnP_w  = (const float*)d_in[21];
    const float* attnP_b  = (const float*)d_in[22];
    const int* KMIds   = (const int*)d_in[23];
    const int* leaves1 = (const int*)d_in[24];
    const int* anc1    = (const int*)d_in[25];
    const int* leaves2 = (const int*)d_in[26];
    const int* anc2    = (const int*)d_in[27];
    const int* mapInfo = (const int*)d_in[28];
    const int* X_len   = (const int*)d_in[29];

    char* ws = (char*)d_ws;
    float* out = (float*)d_out;
    typedef __hip_bfloat16 bf16;

    // ---- workspace layout (bytes) ----
    const size_t R0 = 0;            // 67,108,864 multi-use region
    const size_t R1 = 67108864;     // 16,777,216 : gruo f32
    const size_t R2 = 83886080;     // 16,777,216 : era f32
    const size_t R3 = 100663296;    // 20,971,520 : At_hi/At_lo; later slotw/readv
    size_t P = 121634816;
    const size_t EMBHI = P; P += 1048576;   // embMT hi [256][2048]
    const size_t EMBLO = P; P += 1048576;   // embMT lo
    const size_t OWF  = P; P += 1835008;    // out_w^T f16 [2048][448]
    const size_t WIHI = P; P += 393216;
    const size_t WILO = P; P += 393216;
    const size_t WEHI = P; P += 131072;
    const size_t WELO = P; P += 131072;
    const size_t THHI = P; P += 163840;
    const size_t THLO = P; P += 163840;
    const size_t KMHI = P; P += 65536;
    const size_t KMLO = P; P += 65536;
    const size_t WRG  = P; P += 344064;     // Whh f16 reg-part [112][768] uint
    const size_t WST  = P; P += 49152;      // Whh f16 stream-part [4][768][4] uint
    const size_t PROF = P; P += 65536;
    const size_t BEA  = P; P += 1024;
    const size_t W2O  = P; P += 262144;

    float* PP      = (float*)(ws + R0);
    float* embG    = (float*)(ws + R0 + 12288000);
    float* gx      = (float*)(ws + R0);
    bf16*  Xe_hi   = (bf16*)(ws + R0 + 50331648);
    bf16*  Xe_lo   = (bf16*)(ws + R0 + 58720256);
    bf16*  tran_hi = (bf16*)(ws + R0);
    bf16*  tran_lo = (bf16*)(ws + R0 + 8388608);
    _Float16* F16  = (_Float16*)(ws + R0);
    float* gruo    = (float*)(ws + R1);
    float* era     = (float*)(ws + R2);
    bf16*  At_hi   = (bf16*)(ws + R3);
    bf16*  At_lo   = (bf16*)(ws + R3 + 10485760);
    float* slotw   = (float*)(ws + R3);
    float* readv   = (float*)(ws + R3 + 10485760);
    bf16*  EMBhi = (bf16*)(ws + EMBHI); bf16* EMBlo = (bf16*)(ws + EMBLO);
    _Float16* OWf = (_Float16*)(ws + OWF);
    bf16*  WIhi = (bf16*)(ws + WIHI); bf16* WIlo = (bf16*)(ws + WILO);
    bf16*  WEhi = (bf16*)(ws + WEHI); bf16* WElo = (bf16*)(ws + WELO);
    bf16*  THhi = (bf16*)(ws + THHI); bf16* THlo = (bf16*)(ws + THLO);
    bf16*  KMhi = (bf16*)(ws + KMHI); bf16* KMlo = (bf16*)(ws + KMLO);
    unsigned int* Wrg = (unsigned int*)(ws + WRG);
    unsigned int* Wst = (unsigned int*)(ws + WST);
    float* prof = (float*)(ws + PROF);
    float* bea  = (float*)(ws + BEA);
    float* W2p  = (float*)(ws + W2O);

    // ---- weight packs ----
    k_pack_w2<<<(E_ * 2 * A_ + 255) / 256, 256, 0, stream>>>(Wa_w, W2p);
    k_weaT_split<<<(256 * 256 + 255) / 256, 256, 0, stream>>>(erase_w, add_w, erase_b, add_b, WEhi, WElo, bea);
    k_wih_split<<<(768 * 256 + 255) / 256, 256, 0, stream>>>(gru_Wih, WIhi, WIlo);
    k_tranHT_split<<<(256 * 320 + 255) / 256, 256, 0, stream>>>(tranH_w, THhi, THlo);
    k_outWT_f16<<<(2048 * 448 + 255) / 256, 256, 0, stream>>>(out_w, OWf);
    k_km_split<<<(S_ * E_ + 255) / 256, 256, 0, stream>>>(ini_embd, KMIds, KMhi, KMlo);
    k_wgru_pack<<<(768 * 128 + 255) / 256, 256, 0, stream>>>(gru_Whh, Wrg, Wst);
    k_prof<<<B_, PE_, 0, stream>>>(profiles, emP_w, emP_b, prof);

    // ---- ontology attention -> embedMat planes ----
    {
        dim3 blk(16, 16);
        dim3 grid(4, (TN_ + 63) / 64);
        k_gemm<64, 64, 16, 4, 4><<<grid, blk, 0, stream>>>(ini_embd, W2p, PP, TN_, 256, E_);
    }
    k_group_embed<<<G1N_ + G2N_, 64, 0, stream>>>(PP, Wa_b, Ua_w, ini_embd,
                                                  leaves1, anc1, leaves2, anc2, embG);
    k_embMT<<<(256 * 2048) / 256, 256, 0, stream>>>(embG, mapInfo, EMBhi, EMBlo);

    // ---- Xe = X @ embM (fused f32-A split GEMM, writes Xe planes) ----
    k_mgemmX<<<128 * 2, 256, 0, stream>>>(X, EMBhi, EMBlo, Xe_hi, Xe_lo);

    // ---- era = gates(Xe @ Wea + bea) ----
    k_mgemm3<1, false, 0, 3, 0><<<128 * 2, 256, 0, stream>>>(Xe_hi, Xe_lo, WEhi, WElo,
        bea, era, nullptr, nullptr, 256, 256, 2);

    // ---- gx = Xe @ Wih^T + bih ----
    k_mgemm3<0, false, 0, 3, 0><<<128 * 6, 256, 0, stream>>>(Xe_hi, Xe_lo, WIhi, WIlo,
        gru_bih, gx, nullptr, nullptr, 256, 768, 6);

    // ---- GRU scan v5 ----
    k_gru5<<<256, 768, 0, stream>>>(gx, Wrg, (const uint4*)Wst, gru_bhh, X_len,
                                    gruo, At_hi, At_lo);
    k_fill_tp<<<(M_ * PE_) / 256, 256, 0, stream>>>(prof, At_hi, At_lo);

    // ---- tran = [gruo|prof] @ tranH + b ----
    k_mgemm3<0, false, 1, 3, 0><<<128 * 2, 256, 0, stream>>>(At_hi, At_lo, THhi, THlo,
        tranH_b, nullptr, tran_hi, tran_lo, 320, 256, 2);

    // ---- slot logits = tran @ KM^T ----
    k_mgemm3<0, false, 0, 3, 0><<<128 * 1, 256, 0, stream>>>(tran_hi, tran_lo, KMhi, KMlo,
        nullptr, slotw, nullptr, nullptr, 256, 128, 1);

    k_softmax128<<<M_, 64, 0, stream>>>(slotw);
    k_mem<<<B_, 256, 0, stream>>>(slotw, era, iniVam, readv);
    k_build_final<<<M_, 256, 0, stream>>>(gruo, readv, prof, attnP_w, attnP_b, F16);

    // ---- logits = F @ out_w + out_b (f16 1-phase MFMA) ----
    k_mgemm3<0, false, 0, 1, 1><<<128 * 16, 256, 0, stream>>>(
        (const bf16*)F16, nullptr, (const bf16*)OWf, nullptr,
        out_b, out, nullptr, nullptr, 448, 2000, 16);

    k_softmax2000<<<M_, 256, 0, stream>>>(out);
}